// Round 5
// baseline (1034.966 us; speedup 1.0000x reference)
//
#include <hip/hip_runtime.h>
#include <math.h>

#define N_NODES 100000
#define N_EDGES 1600000
#define NBLK_SCAN ((N_NODES + 255) / 256)   // 391
#define NPAD 100064                          // 64-row padded for GEMM staging
#define NBINS 128

typedef __attribute__((ext_vector_type(8))) short bf16x8;
typedef __attribute__((ext_vector_type(4))) float f32x4;

__device__ __forceinline__ unsigned short f2bf(float f) {
    unsigned int u = __builtin_bit_cast(unsigned int, f);
    u += 0x7fffu + ((u >> 16) & 1u);          // RNE
    return (unsigned short)(u >> 16);
}
__device__ __forceinline__ float bflo2f(unsigned int u) {   // low 16 bits = bf16
    return __builtin_bit_cast(float, u << 16);
}
__device__ __forceinline__ float bfhi2f(unsigned int u) {   // high 16 bits = bf16
    return __builtin_bit_cast(float, u & 0xffff0000u);
}

// ---------------- degree ----------------

__global__ void deg_count_kernel(const int* __restrict__ dst, int* deg) {
    int e = blockIdx.x * blockDim.x + threadIdx.x;
    if (e < N_EDGES) atomicAdd(&deg[dst[e]], 1);
}

__global__ void dinv_kernel(const int* __restrict__ deg, float* dinv) {
    int i = blockIdx.x * blockDim.x + threadIdx.x;
    if (i < N_NODES) dinv[i] = rsqrtf(1.0f + (float)deg[i]);  // +1 self-loop
}

// ---------------- exclusive scan (3-phase) ----------------

__global__ void scan1_kernel(const int* __restrict__ deg, int* __restrict__ ex,
                             int* __restrict__ bsum) {
    __shared__ int tmp[256];
    int i = blockIdx.x * 256 + threadIdx.x;
    int v = (i < N_NODES) ? deg[i] : 0;
    tmp[threadIdx.x] = v;
    __syncthreads();
    for (int off = 1; off < 256; off <<= 1) {
        int t = (threadIdx.x >= off) ? tmp[threadIdx.x - off] : 0;
        __syncthreads();
        tmp[threadIdx.x] += t;
        __syncthreads();
    }
    if (i < N_NODES) ex[i] = tmp[threadIdx.x] - v;
    if (threadIdx.x == 255) bsum[blockIdx.x] = tmp[255];
}

__global__ void scan2_kernel(int* bsum) {
    __shared__ int tmp[512];
    int i = threadIdx.x;
    int v = (i < NBLK_SCAN) ? bsum[i] : 0;
    tmp[i] = v;
    __syncthreads();
    for (int off = 1; off < 512; off <<= 1) {
        int t = (i >= off) ? tmp[i - off] : 0;
        __syncthreads();
        tmp[i] += t;
        __syncthreads();
    }
    if (i < NBLK_SCAN) bsum[i] = tmp[i] - v;
}

__global__ void scan3_kernel(int* rowptr, const int* __restrict__ bsum) {
    int i = blockIdx.x * 256 + threadIdx.x;
    if (i < N_NODES) rowptr[i] += bsum[blockIdx.x];
}

__global__ void copy_rowp_kernel(const int* __restrict__ rowp, int* __restrict__ curs) {
    int i = blockIdx.x * 256 + threadIdx.x;
    if (i < N_NODES) curs[i] = rowp[i];
}

// ---------------- degree-sorted node order (counting sort, 128 bins) ----------------

__global__ void hist_kernel(const int* __restrict__ deg, int* hist) {
    int i = blockIdx.x * blockDim.x + threadIdx.x;
    if (i < N_NODES) atomicAdd(&hist[min(deg[i], NBINS - 1)], 1);
}

__global__ void binscan_kernel(int* hist) {   // <<<1,128>>>, in-place exclusive
    __shared__ int tmp[NBINS];
    int i = threadIdx.x;
    int v = hist[i];
    tmp[i] = v;
    __syncthreads();
    for (int off = 1; off < NBINS; off <<= 1) {
        int t = (i >= off) ? tmp[i - off] : 0;
        __syncthreads();
        tmp[i] += t;
        __syncthreads();
    }
    hist[i] = tmp[i] - v;
}

__global__ void order_kernel(const int* __restrict__ deg, int* hist, int* __restrict__ order) {
    int i = blockIdx.x * blockDim.x + threadIdx.x;
    if (i < N_NODES) {
        int pos = atomicAdd(&hist[min(deg[i], NBINS - 1)], 1);
        order[pos] = i;
    }
}

// ---------------- edge scatter (counting sort by dst, AoS 8B record, NT store) ----------------

__global__ void scatter_kernel(const int* __restrict__ src, const int* __restrict__ dst,
                               const float* __restrict__ dinv,
                               int* curs, int2* __restrict__ sedge) {
    int e = blockIdx.x * blockDim.x + threadIdx.x;
    if (e >= N_EDGES) return;
    int d = dst[e], s = src[e];
    int pos = atomicAdd(&curs[d], 1);   // curs pre-initialized to rowptr
    long long rec = ((long long)(unsigned int)__float_as_int(dinv[s]) << 32)
                  | (unsigned int)s;
    __builtin_nontemporal_store(rec, (long long*)(sedge + pos));
}

// ---------------- conversions ----------------

__global__ void cvt_x_kernel(const float* __restrict__ x, unsigned short* __restrict__ xb) {
    long i = (long)blockIdx.x * blockDim.x + threadIdx.x;   // over n/4
    if (i >= (long)N_NODES * 128 / 4) return;
    float4 v = ((const float4*)x)[i];
    ushort4 o;
    o.x = f2bf(v.x); o.y = f2bf(v.y); o.z = f2bf(v.z); o.w = f2bf(v.w);
    ((ushort4*)xb)[i] = o;
}

// Wt[m][k] = bf16(W[k][m])
__global__ void cvt_w_kernel(const float* __restrict__ W, unsigned short* __restrict__ Wt,
                             int K, int M) {
    int i = blockIdx.x * blockDim.x + threadIdx.x;
    if (i >= K * M) return;
    int k = i / M, m = i % M;
    Wt[(long)m * K + k] = f2bf(W[i]);
}

// ---------------- CSR gather aggregation (bf16 in, bf16/f32 out) ----------------
// one 64-lane wave per dst node (degree-sorted order); lane owns C/64 channels
template<int C, bool BIAS, bool RELU, bool LOGSM, bool OUTF32>
__global__ void agg_csr_kernel(const unsigned short* __restrict__ h,
                               const float* __restrict__ dinv,
                               const int* __restrict__ rowptr, const int* __restrict__ deg,
                               const int2* __restrict__ sedge,
                               const int* __restrict__ order,
                               const float* __restrict__ bias, void* __restrict__ outv) {
    constexpr int V = C / 64;  // 2 for C=128, 1 for C=64
    int gw = (int)((blockIdx.x * (long)blockDim.x + threadIdx.x) >> 6);
    int lane = threadIdx.x & 63;
    if (gw >= N_NODES) return;
    int node = order[gw];

    float di = dinv[node];
    int st = rowptr[node];
    int cnt = deg[node];
    float a0, a1 = 0.0f;
    if constexpr (V == 2) {
        unsigned int u = ((const unsigned int*)(h + (long)node * C))[lane];
        a0 = di * bflo2f(u); a1 = di * bfhi2f(u);
    } else {
        a0 = di * bflo2f(h[(long)node * C + lane]);
    }

    int k = 0;
    for (; k + 4 <= cnt; k += 4) {
        int2 r0 = sedge[st + k],     r1 = sedge[st + k + 1];
        int2 r2 = sedge[st + k + 2], r3 = sedge[st + k + 3];
        float w0 = __int_as_float(r0.y), w1 = __int_as_float(r1.y);
        float w2 = __int_as_float(r2.y), w3 = __int_as_float(r3.y);
        if constexpr (V == 2) {
            unsigned int u0 = ((const unsigned int*)(h + (long)r0.x * C))[lane];
            unsigned int u1 = ((const unsigned int*)(h + (long)r1.x * C))[lane];
            unsigned int u2 = ((const unsigned int*)(h + (long)r2.x * C))[lane];
            unsigned int u3 = ((const unsigned int*)(h + (long)r3.x * C))[lane];
            a0 += w0 * bflo2f(u0); a1 += w0 * bfhi2f(u0);
            a0 += w1 * bflo2f(u1); a1 += w1 * bfhi2f(u1);
            a0 += w2 * bflo2f(u2); a1 += w2 * bfhi2f(u2);
            a0 += w3 * bflo2f(u3); a1 += w3 * bfhi2f(u3);
        } else {
            a0 += w0 * bflo2f(h[(long)r0.x * C + lane]);
            a0 += w1 * bflo2f(h[(long)r1.x * C + lane]);
            a0 += w2 * bflo2f(h[(long)r2.x * C + lane]);
            a0 += w3 * bflo2f(h[(long)r3.x * C + lane]);
        }
    }
    for (; k < cnt; ++k) {
        int2 r = sedge[st + k];
        float w = __int_as_float(r.y);
        if constexpr (V == 2) {
            unsigned int u = ((const unsigned int*)(h + (long)r.x * C))[lane];
            a0 += w * bflo2f(u); a1 += w * bfhi2f(u);
        } else {
            a0 += w * bflo2f(h[(long)r.x * C + lane]);
        }
    }

    a0 *= di; a1 *= di;
    if constexpr (BIAS) {
        if constexpr (V == 2) { a0 += bias[lane * 2]; a1 += bias[lane * 2 + 1]; }
        else a0 += bias[lane];
    }
    if constexpr (RELU) { a0 = fmaxf(a0, 0.0f); a1 = fmaxf(a1, 0.0f); }
    if constexpr (LOGSM) {  // V==1 only
        float m = a0;
#pragma unroll
        for (int o = 32; o > 0; o >>= 1) m = fmaxf(m, __shfl_xor(m, o));
        float e = expf(a0 - m), s = e;
#pragma unroll
        for (int o = 32; o > 0; o >>= 1) s += __shfl_xor(s, o);
        a0 = a0 - m - logf(s);
    }
    if constexpr (OUTF32) {
        float* out = (float*)outv;
        if constexpr (V == 2) {
            float2 r; r.x = a0; r.y = a1;
            *(float2*)(out + (long)node * C + lane * 2) = r;
        } else {
            out[(long)node * C + lane] = a0;
        }
    } else {
        unsigned short* out = (unsigned short*)outv;
        if constexpr (V == 2) {
            unsigned int up = (unsigned int)f2bf(a0) | ((unsigned int)f2bf(a1) << 16);
            ((unsigned int*)(out + (long)node * C))[lane] = up;
        } else {
            out[(long)node * C + lane] = f2bf(a0);
        }
    }
}

// ---------------- bf16 MFMA GEMM ----------------
// C[N,M](bf16) = A[N,K](bf16) @ Wt[M,K]^T (+bias)(relu)
// 64x64 block tile, 4 waves 2x2, each wave 32x32 via mfma_f32_16x16x32_bf16.
template<int K, int M, bool BIAS, bool RELU>
__global__ __launch_bounds__(256) void gemm_mfma_kernel(
        const unsigned short* __restrict__ A,   // [NPAD][K]
        const unsigned short* __restrict__ Bt,  // [M][K]
        const float* __restrict__ bias,         // [M]
        unsigned short* __restrict__ Cb,        // [NPAD][M]
        int N) {
    constexpr int KC = K / 8;                    // 16B chunks per row
    __shared__ unsigned short As[64 * K];
    __shared__ unsigned short Bs[64 * K];

    int tid = threadIdx.x;
    int row0 = blockIdx.x * 64;
    int col0 = blockIdx.y * 64;

    const unsigned short* Ap = A + (long)row0 * K;
    const unsigned short* Bp = Bt + (long)col0 * K;

    // stage both panels; LDS byte = (c*16) ^ ((row&7)<<4)
    for (int c = tid; c < 64 * KC; c += 256) {
        int r = c / KC;
        unsigned int swz = ((unsigned int)c * 16u) ^ ((unsigned int)(r & 7) << 4);
        bf16x8 va = *(const bf16x8*)(Ap + c * 8);
        bf16x8 vb = *(const bf16x8*)(Bp + c * 8);
        *(bf16x8*)((char*)As + swz) = va;
        *(bf16x8*)((char*)Bs + swz) = vb;
    }
    __syncthreads();

    int lane = tid & 63;
    int wv = tid >> 6;
    int wr = wv >> 1, wc = wv & 1;      // wave tile origin (wr*32, wc*32)
    int lr = lane & 15;
    int kg = lane >> 4;                 // k-group: k = kg*8 + j

    f32x4 acc[2][2] = {};

    for (int k0 = 0; k0 < K; k0 += 32) {
        bf16x8 a[2], b[2];
#pragma unroll
        for (int mi = 0; mi < 2; ++mi) {
            int r = wr * 32 + mi * 16 + lr;
            unsigned int byteo = (unsigned int)((r * K + k0 + kg * 8) * 2);
            byteo ^= (unsigned int)((r & 7) << 4);
            a[mi] = *(const bf16x8*)((const char*)As + byteo);
        }
#pragma unroll
        for (int ni = 0; ni < 2; ++ni) {
            int r = wc * 32 + ni * 16 + lr;
            unsigned int byteo = (unsigned int)((r * K + k0 + kg * 8) * 2);
            byteo ^= (unsigned int)((r & 7) << 4);
            b[ni] = *(const bf16x8*)((const char*)Bs + byteo);
        }
#pragma unroll
        for (int mi = 0; mi < 2; ++mi)
#pragma unroll
            for (int ni = 0; ni < 2; ++ni)
                acc[mi][ni] = __builtin_amdgcn_mfma_f32_16x16x32_bf16(
                    a[mi], b[ni], acc[mi][ni], 0, 0, 0);
    }

    // epilogue: C/D layout col=lane&15, row=(lane>>4)*4+i
#pragma unroll
    for (int mi = 0; mi < 2; ++mi) {
#pragma unroll
        for (int ni = 0; ni < 2; ++ni) {
            int col = col0 + wc * 32 + ni * 16 + lr;
            float bv = BIAS ? bias[col] : 0.0f;
#pragma unroll
            for (int i = 0; i < 4; ++i) {
                int row = row0 + wr * 32 + mi * 16 + kg * 4 + i;
                if (row < N) {
                    float v = acc[mi][ni][i] + bv;
                    if (RELU) v = fmaxf(v, 0.0f);
                    Cb[(long)row * M + col] = f2bf(v);
                }
            }
        }
    }
}

// ---------------- launch ----------------

extern "C" void kernel_launch(void* const* d_in, const int* in_sizes, int n_in,
                              void* d_out, int out_size, void* d_ws, size_t ws_size,
                              hipStream_t stream) {
    const float* x  = (const float*)d_in[0];
    const int* edge = (const int*)d_in[1];
    const float* W1 = (const float*)d_in[2];
    const float* b1 = (const float*)d_in[3];
    const float* W2 = (const float*)d_in[4];
    const float* b2 = (const float*)d_in[5];
    const float* W3 = (const float*)d_in[6];
    const float* b3 = (const float*)d_in[7];
    float* out = (float*)d_out;

    const int* src = edge;
    const int* dst = edge + N_EDGES;

    // workspace: fp32/int CSR region, then bf16 buffers
    float* ws    = (float*)d_ws;
    float* dinv  = ws;                                   // N
    int*   degi  = (int*)(ws + 100000);
    int*   rowp  = (int*)(ws + 200000);
    int*   curs  = (int*)(ws + 300000);
    int*   bsum  = (int*)(ws + 400000);
    int2*  sedge = (int2*)(ws + 401024);                 // E * 8B (8B-aligned)
    unsigned short* P1  = (unsigned short*)(ws + 3601024);   // [NPAD][128]
    unsigned short* P2  = P1 + (size_t)NPAD * 128;           // [NPAD][128]
    unsigned short* P3  = P2 + (size_t)NPAD * 128;           // [NPAD][256]
    unsigned short* Wt1 = P3 + (size_t)NPAD * 256;           // [256][128]
    unsigned short* Wt2 = Wt1 + 128 * 256;                   // [128][256]
    unsigned short* Wt3 = Wt2 + 256 * 128;                   // [64][128]
    int*   order = (int*)(Wt3 + 64 * 128);                   // N ints
    int*   hist  = order + N_NODES;                          // NBINS ints

    const int BT = 256;
    int gN = (N_NODES + BT - 1) / BT;
    int gE = (N_EDGES + BT - 1) / BT;
    int gAgg = (int)(((long)N_NODES * 64 + BT - 1) / BT);
    int gRows = (N_NODES + 63) / 64;   // 1563

    // --- degree + dinv + CSR ---
    hipMemsetAsync(degi, 0, N_NODES * sizeof(int), stream);
    deg_count_kernel<<<gE, BT, 0, stream>>>(dst, degi);
    dinv_kernel<<<gN, BT, 0, stream>>>(degi, dinv);
    scan1_kernel<<<NBLK_SCAN, 256, 0, stream>>>(degi, rowp, bsum);
    scan2_kernel<<<1, 512, 0, stream>>>(bsum);
    scan3_kernel<<<NBLK_SCAN, 256, 0, stream>>>(rowp, bsum);
    copy_rowp_kernel<<<NBLK_SCAN, 256, 0, stream>>>(rowp, curs);
    scatter_kernel<<<gE, BT, 0, stream>>>(src, dst, dinv, curs, sedge);

    // --- degree-sorted node order ---
    hipMemsetAsync(hist, 0, NBINS * sizeof(int), stream);
    hist_kernel<<<gN, BT, 0, stream>>>(degi, hist);
    binscan_kernel<<<1, NBINS, 0, stream>>>(hist);
    order_kernel<<<gN, BT, 0, stream>>>(degi, hist, order);

    // --- conversions ---
    cvt_x_kernel<<<(int)(((long)N_NODES * 128 / 4 + BT - 1) / BT), BT, 0, stream>>>(x, P1);
    cvt_w_kernel<<<(128 * 256 + BT - 1) / BT, BT, 0, stream>>>(W1, Wt1, 128, 256);
    cvt_w_kernel<<<(256 * 128 + BT - 1) / BT, BT, 0, stream>>>(W2, Wt2, 256, 128);
    cvt_w_kernel<<<(128 * 64 + BT - 1) / BT, BT, 0, stream>>>(W3, Wt3, 128, 64);

    // --- layer 1: agg(x) [P1->P2], gemm 128->256 +b1 +relu [P2->P3] ---
    agg_csr_kernel<128, false, false, false, false><<<gAgg, BT, 0, stream>>>(
        P1, dinv, rowp, degi, sedge, order, nullptr, P2);
    {
        dim3 g(gRows, 4);
        gemm_mfma_kernel<128, 256, true, true><<<g, BT, 0, stream>>>(P2, Wt1, b1, P3, N_NODES);
    }

    // --- layer 2: gemm 256->128 [P3->P1], agg +b2 +relu [P1->P2] ---
    {
        dim3 g(gRows, 2);
        gemm_mfma_kernel<256, 128, false, false><<<g, BT, 0, stream>>>(P3, Wt2, nullptr, P1, N_NODES);
    }
    agg_csr_kernel<128, true, true, false, false><<<gAgg, BT, 0, stream>>>(
        P1, dinv, rowp, degi, sedge, order, b2, P2);

    // --- layer 3: gemm 128->64 [P2->P1], agg +b3 +relu +logsm [P1->out] ---
    {
        dim3 g(gRows, 1);
        gemm_mfma_kernel<128, 64, false, false><<<g, BT, 0, stream>>>(P2, Wt3, nullptr, P1, N_NODES);
    }
    agg_csr_kernel<64, true, true, true, true><<<gAgg, BT, 0, stream>>>(
        P1, dinv, rowp, degi, sedge, order, b3, out);

    (void)in_sizes; (void)n_in; (void)out_size; (void)ws_size;
}

// Round 6
// 523.883 us; speedup vs baseline: 1.9756x; 1.9756x over previous
//
#include <hip/hip_runtime.h>
#include <math.h>

#define N_NODES 100000
#define N_EDGES 1600000
#define NBLK_SCAN ((N_NODES + 255) / 256)   // 391
#define NBLK_E ((N_EDGES + 255) / 256)      // 6250
#define NPAD 100064                          // 64-row padded for GEMM staging
#define NBUCK 25                             // dst>>12 buckets (4096 nodes each)

typedef __attribute__((ext_vector_type(8))) short bf16x8;
typedef __attribute__((ext_vector_type(4))) float f32x4;

__device__ __forceinline__ unsigned short f2bf(float f) {
    unsigned int u = __builtin_bit_cast(unsigned int, f);
    u += 0x7fffu + ((u >> 16) & 1u);          // RNE
    return (unsigned short)(u >> 16);
}
__device__ __forceinline__ float bflo2f(unsigned int u) {   // low 16 bits = bf16
    return __builtin_bit_cast(float, u << 16);
}
__device__ __forceinline__ float bfhi2f(unsigned int u) {   // high 16 bits = bf16
    return __builtin_bit_cast(float, u & 0xffff0000u);
}

// ---------------- degree ----------------

__global__ void deg_count_kernel(const int* __restrict__ dst, int* deg) {
    int e = blockIdx.x * blockDim.x + threadIdx.x;
    if (e < N_EDGES) atomicAdd(&deg[dst[e]], 1);
}

__global__ void dinv_kernel(const int* __restrict__ deg, float* dinv) {
    int i = blockIdx.x * blockDim.x + threadIdx.x;
    if (i < N_NODES) dinv[i] = rsqrtf(1.0f + (float)deg[i]);  // +1 self-loop
}

// ---------------- exclusive scan over nodes (3-phase) ----------------

__global__ void scan1_kernel(const int* __restrict__ deg, int* __restrict__ ex,
                             int* __restrict__ bsum) {
    __shared__ int tmp[256];
    int i = blockIdx.x * 256 + threadIdx.x;
    int v = (i < N_NODES) ? deg[i] : 0;
    tmp[threadIdx.x] = v;
    __syncthreads();
    for (int off = 1; off < 256; off <<= 1) {
        int t = (threadIdx.x >= off) ? tmp[threadIdx.x - off] : 0;
        __syncthreads();
        tmp[threadIdx.x] += t;
        __syncthreads();
    }
    if (i < N_NODES) ex[i] = tmp[threadIdx.x] - v;
    if (threadIdx.x == 255) bsum[blockIdx.x] = tmp[255];
}

__global__ void scan2_kernel(int* bsum) {
    __shared__ int tmp[512];
    int i = threadIdx.x;
    int v = (i < NBLK_SCAN) ? bsum[i] : 0;
    tmp[i] = v;
    __syncthreads();
    for (int off = 1; off < 512; off <<= 1) {
        int t = (i >= off) ? tmp[i - off] : 0;
        __syncthreads();
        tmp[i] += t;
        __syncthreads();
    }
    if (i < NBLK_SCAN) bsum[i] = tmp[i] - v;
}

__global__ void scan3_kernel(int* rowptr, const int* __restrict__ bsum) {
    int i = blockIdx.x * 256 + threadIdx.x;
    if (i < N_NODES) rowptr[i] += bsum[blockIdx.x];
}

__global__ void copy_rowp_kernel(const int* __restrict__ rowp, int* __restrict__ curs) {
    int i = blockIdx.x * 256 + threadIdx.x;
    if (i < N_NODES) curs[i] = rowp[i];
}

// ---------------- two-level edge sort by dst ----------------
// pass 1: per-(bucket, block) counts — NO contended global atomics
__global__ void part_count_kernel(const int* __restrict__ dst, int* __restrict__ bcnt) {
    __shared__ int lh[NBUCK];
    int tid = threadIdx.x;
    if (tid < NBUCK) lh[tid] = 0;
    __syncthreads();
    int e = blockIdx.x * 256 + tid;
    if (e < N_EDGES) atomicAdd(&lh[dst[e] >> 12], 1);
    __syncthreads();
    if (tid < NBUCK) bcnt[tid * NBLK_E + blockIdx.x] = lh[tid];
}

// pass 2: per-bucket exclusive scan over blocks (one wave per bucket)
__global__ void part_scan_kernel(int* __restrict__ bcnt, int* __restrict__ btot) {
    int bu = blockIdx.x, lane = threadIdx.x;   // 64 threads
    int base = 0;
    for (int i0 = 0; i0 < NBLK_E; i0 += 64) {
        int i = i0 + lane;
        int v = (i < NBLK_E) ? bcnt[bu * NBLK_E + i] : 0;
        int orig = v;
#pragma unroll
        for (int off = 1; off < 64; off <<= 1) {
            int t = __shfl_up(v, off);
            if (lane >= off) v += t;
        }
        if (i < NBLK_E) bcnt[bu * NBLK_E + i] = base + v - orig;
        base += __shfl(v, 63);
    }
    if (lane == 0) btot[bu] = base;
}

__global__ void bbase_scan_kernel(const int* __restrict__ btot, int* __restrict__ bbase) {
    int acc = 0;
    for (int i = 0; i < NBUCK; ++i) { bbase[i] = acc; acc += btot[i]; }
}

// pass 3: partition edges into bucket-contiguous (src,dst) records
__global__ void part_scatter_kernel(const int* __restrict__ src, const int* __restrict__ dst,
                                    const int* __restrict__ bcnt, const int* __restrict__ bbase,
                                    int2* __restrict__ part) {
    __shared__ int lh[NBUCK];
    int tid = threadIdx.x;
    if (tid < NBUCK) lh[tid] = 0;
    __syncthreads();
    int e = blockIdx.x * 256 + tid;
    if (e >= N_EDGES) return;
    int s = src[e], d = dst[e];
    int bu = d >> 12;
    int lr = atomicAdd(&lh[bu], 1);
    int pos = bbase[bu] + bcnt[bu * NBLK_E + blockIdx.x] + lr;
    int2 rec; rec.x = s; rec.y = d;
    part[pos] = rec;
}

// pass 4: final per-node scatter; stores land in an L2-resident ~512KB region
__global__ void final_scatter_kernel(const int2* __restrict__ part,
                                     const float* __restrict__ dinv,
                                     int* curs, int2* __restrict__ sedge) {
    int e = blockIdx.x * 256 + threadIdx.x;
    if (e >= N_EDGES) return;
    int2 r = part[e];
    int pos = atomicAdd(&curs[r.y], 1);   // curs pre-initialized to rowptr
    int2 rec; rec.x = r.x; rec.y = __float_as_int(dinv[r.x]);
    sedge[pos] = rec;
}

// ---------------- conversions ----------------

__global__ void cvt_x_kernel(const float* __restrict__ x, unsigned short* __restrict__ xb) {
    long i = (long)blockIdx.x * blockDim.x + threadIdx.x;   // over n/4
    if (i >= (long)N_NODES * 128 / 4) return;
    float4 v = ((const float4*)x)[i];
    ushort4 o;
    o.x = f2bf(v.x); o.y = f2bf(v.y); o.z = f2bf(v.z); o.w = f2bf(v.w);
    ((ushort4*)xb)[i] = o;
}

// Wt[m][k] = bf16(W[k][m])
__global__ void cvt_w_kernel(const float* __restrict__ W, unsigned short* __restrict__ Wt,
                             int K, int M) {
    int i = blockIdx.x * blockDim.x + threadIdx.x;
    if (i >= K * M) return;
    int k = i / M, m = i % M;
    Wt[(long)m * K + k] = f2bf(W[i]);
}

// ---------------- CSR gather aggregation (bf16 in, bf16/f32 out) ----------------
// one 64-lane wave per dst node; lane owns C/64 channels
template<int C, bool BIAS, bool RELU, bool LOGSM, bool OUTF32>
__global__ void agg_csr_kernel(const unsigned short* __restrict__ h,
                               const float* __restrict__ dinv,
                               const int* __restrict__ rowptr, const int* __restrict__ deg,
                               const int2* __restrict__ sedge,
                               const float* __restrict__ bias, void* __restrict__ outv) {
    constexpr int V = C / 64;  // 2 for C=128, 1 for C=64
    int gw = (int)((blockIdx.x * (long)blockDim.x + threadIdx.x) >> 6);
    int lane = threadIdx.x & 63;
    if (gw >= N_NODES) return;

    float di = dinv[gw];
    int st = rowptr[gw];
    int cnt = deg[gw];
    float a0, a1 = 0.0f;
    if constexpr (V == 2) {
        unsigned int u = ((const unsigned int*)(h + (long)gw * C))[lane];
        a0 = di * bflo2f(u); a1 = di * bfhi2f(u);
    } else {
        a0 = di * bflo2f(h[(long)gw * C + lane]);
    }

    int k = 0;
    for (; k + 4 <= cnt; k += 4) {
        int2 r0 = sedge[st + k],     r1 = sedge[st + k + 1];
        int2 r2 = sedge[st + k + 2], r3 = sedge[st + k + 3];
        float w0 = __int_as_float(r0.y), w1 = __int_as_float(r1.y);
        float w2 = __int_as_float(r2.y), w3 = __int_as_float(r3.y);
        if constexpr (V == 2) {
            unsigned int u0 = ((const unsigned int*)(h + (long)r0.x * C))[lane];
            unsigned int u1 = ((const unsigned int*)(h + (long)r1.x * C))[lane];
            unsigned int u2 = ((const unsigned int*)(h + (long)r2.x * C))[lane];
            unsigned int u3 = ((const unsigned int*)(h + (long)r3.x * C))[lane];
            a0 += w0 * bflo2f(u0); a1 += w0 * bfhi2f(u0);
            a0 += w1 * bflo2f(u1); a1 += w1 * bfhi2f(u1);
            a0 += w2 * bflo2f(u2); a1 += w2 * bfhi2f(u2);
            a0 += w3 * bflo2f(u3); a1 += w3 * bfhi2f(u3);
        } else {
            a0 += w0 * bflo2f(h[(long)r0.x * C + lane]);
            a0 += w1 * bflo2f(h[(long)r1.x * C + lane]);
            a0 += w2 * bflo2f(h[(long)r2.x * C + lane]);
            a0 += w3 * bflo2f(h[(long)r3.x * C + lane]);
        }
    }
    for (; k < cnt; ++k) {
        int2 r = sedge[st + k];
        float w = __int_as_float(r.y);
        if constexpr (V == 2) {
            unsigned int u = ((const unsigned int*)(h + (long)r.x * C))[lane];
            a0 += w * bflo2f(u); a1 += w * bfhi2f(u);
        } else {
            a0 += w * bflo2f(h[(long)r.x * C + lane]);
        }
    }

    a0 *= di; a1 *= di;
    if constexpr (BIAS) {
        if constexpr (V == 2) { a0 += bias[lane * 2]; a1 += bias[lane * 2 + 1]; }
        else a0 += bias[lane];
    }
    if constexpr (RELU) { a0 = fmaxf(a0, 0.0f); a1 = fmaxf(a1, 0.0f); }
    if constexpr (LOGSM) {  // V==1 only
        float m = a0;
#pragma unroll
        for (int o = 32; o > 0; o >>= 1) m = fmaxf(m, __shfl_xor(m, o));
        float e = expf(a0 - m), s = e;
#pragma unroll
        for (int o = 32; o > 0; o >>= 1) s += __shfl_xor(s, o);
        a0 = a0 - m - logf(s);
    }
    if constexpr (OUTF32) {
        float* out = (float*)outv;
        if constexpr (V == 2) {
            float2 r; r.x = a0; r.y = a1;
            *(float2*)(out + (long)gw * C + lane * 2) = r;
        } else {
            out[(long)gw * C + lane] = a0;
        }
    } else {
        unsigned short* out = (unsigned short*)outv;
        if constexpr (V == 2) {
            unsigned int up = (unsigned int)f2bf(a0) | ((unsigned int)f2bf(a1) << 16);
            ((unsigned int*)(out + (long)gw * C))[lane] = up;
        } else {
            out[(long)gw * C + lane] = f2bf(a0);
        }
    }
}

// ---------------- bf16 MFMA GEMM ----------------
// C[N,M](bf16) = A[N,K](bf16) @ Wt[M,K]^T (+bias)(relu)
// 64x64 block tile, 4 waves 2x2, each wave 32x32 via mfma_f32_16x16x32_bf16.
template<int K, int M, bool BIAS, bool RELU>
__global__ __launch_bounds__(256) void gemm_mfma_kernel(
        const unsigned short* __restrict__ A,   // [NPAD][K]
        const unsigned short* __restrict__ Bt,  // [M][K]
        const float* __restrict__ bias,         // [M]
        unsigned short* __restrict__ Cb,        // [NPAD][M]
        int N) {
    constexpr int KC = K / 8;                    // 16B chunks per row
    __shared__ unsigned short As[64 * K];
    __shared__ unsigned short Bs[64 * K];

    int tid = threadIdx.x;
    int row0 = blockIdx.x * 64;
    int col0 = blockIdx.y * 64;

    const unsigned short* Ap = A + (long)row0 * K;
    const unsigned short* Bp = Bt + (long)col0 * K;

    // stage both panels; LDS byte = (c*16) ^ ((row&7)<<4)
    for (int c = tid; c < 64 * KC; c += 256) {
        int r = c / KC;
        unsigned int swz = ((unsigned int)c * 16u) ^ ((unsigned int)(r & 7) << 4);
        bf16x8 va = *(const bf16x8*)(Ap + c * 8);
        bf16x8 vb = *(const bf16x8*)(Bp + c * 8);
        *(bf16x8*)((char*)As + swz) = va;
        *(bf16x8*)((char*)Bs + swz) = vb;
    }
    __syncthreads();

    int lane = tid & 63;
    int wv = tid >> 6;
    int wr = wv >> 1, wc = wv & 1;      // wave tile origin (wr*32, wc*32)
    int lr = lane & 15;
    int kg = lane >> 4;                 // k-group: k = kg*8 + j

    f32x4 acc[2][2] = {};

    for (int k0 = 0; k0 < K; k0 += 32) {
        bf16x8 a[2], b[2];
#pragma unroll
        for (int mi = 0; mi < 2; ++mi) {
            int r = wr * 32 + mi * 16 + lr;
            unsigned int byteo = (unsigned int)((r * K + k0 + kg * 8) * 2);
            byteo ^= (unsigned int)((r & 7) << 4);
            a[mi] = *(const bf16x8*)((const char*)As + byteo);
        }
#pragma unroll
        for (int ni = 0; ni < 2; ++ni) {
            int r = wc * 32 + ni * 16 + lr;
            unsigned int byteo = (unsigned int)((r * K + k0 + kg * 8) * 2);
            byteo ^= (unsigned int)((r & 7) << 4);
            b[ni] = *(const bf16x8*)((const char*)Bs + byteo);
        }
#pragma unroll
        for (int mi = 0; mi < 2; ++mi)
#pragma unroll
            for (int ni = 0; ni < 2; ++ni)
                acc[mi][ni] = __builtin_amdgcn_mfma_f32_16x16x32_bf16(
                    a[mi], b[ni], acc[mi][ni], 0, 0, 0);
    }

    // epilogue: C/D layout col=lane&15, row=(lane>>4)*4+i
#pragma unroll
    for (int mi = 0; mi < 2; ++mi) {
#pragma unroll
        for (int ni = 0; ni < 2; ++ni) {
            int col = col0 + wc * 32 + ni * 16 + lr;
            float bv = BIAS ? bias[col] : 0.0f;
#pragma unroll
            for (int i = 0; i < 4; ++i) {
                int row = row0 + wr * 32 + mi * 16 + kg * 4 + i;
                if (row < N) {
                    float v = acc[mi][ni][i] + bv;
                    if (RELU) v = fmaxf(v, 0.0f);
                    Cb[(long)row * M + col] = f2bf(v);
                }
            }
        }
    }
}

// ---------------- launch ----------------

extern "C" void kernel_launch(void* const* d_in, const int* in_sizes, int n_in,
                              void* d_out, int out_size, void* d_ws, size_t ws_size,
                              hipStream_t stream) {
    const float* x  = (const float*)d_in[0];
    const int* edge = (const int*)d_in[1];
    const float* W1 = (const float*)d_in[2];
    const float* b1 = (const float*)d_in[3];
    const float* W2 = (const float*)d_in[4];
    const float* b2 = (const float*)d_in[5];
    const float* W3 = (const float*)d_in[6];
    const float* b3 = (const float*)d_in[7];
    float* out = (float*)d_out;

    const int* src = edge;
    const int* dst = edge + N_EDGES;

    // workspace: fp32/int CSR region, then bf16 buffers
    float* ws    = (float*)d_ws;
    float* dinv  = ws;                                   // N
    int*   degi  = (int*)(ws + 100000);
    int*   rowp  = (int*)(ws + 200000);
    int*   curs  = (int*)(ws + 300000);
    int*   bsum  = (int*)(ws + 400000);                  // 391 (alloc 512)
    int*   btot  = (int*)(ws + 400512);                  // 25
    int*   bbase = (int*)(ws + 400640);                  // 25 (alloc to 401024)
    int2*  sedge = (int2*)(ws + 401024);                 // E * 8B (8B-aligned)
    unsigned short* P1  = (unsigned short*)(ws + 3601024);   // [NPAD][128]
    unsigned short* P2  = P1 + (size_t)NPAD * 128;           // [NPAD][128]
    unsigned short* P3  = P2 + (size_t)NPAD * 128;           // [NPAD][256]
    unsigned short* Wt1 = P3 + (size_t)NPAD * 256;           // [256][128]
    unsigned short* Wt2 = Wt1 + 128 * 256;                   // [128][256]
    unsigned short* Wt3 = Wt2 + 256 * 128;                   // [64][128]
    // scratch reuse (consumed before P2/P3 are written):
    int*   bcnt  = (int*)P2;                             // [NBUCK][NBLK_E] ints
    int2*  part  = (int2*)P3;                            // E records

    const int BT = 256;
    int gN = (N_NODES + BT - 1) / BT;
    int gE = NBLK_E;
    int gAgg = (int)(((long)N_NODES * 64 + BT - 1) / BT);
    int gRows = (N_NODES + 63) / 64;   // 1563

    // --- degree + dinv + rowptr ---
    hipMemsetAsync(degi, 0, N_NODES * sizeof(int), stream);
    deg_count_kernel<<<gE, BT, 0, stream>>>(dst, degi);
    dinv_kernel<<<gN, BT, 0, stream>>>(degi, dinv);
    scan1_kernel<<<NBLK_SCAN, 256, 0, stream>>>(degi, rowp, bsum);
    scan2_kernel<<<1, 512, 0, stream>>>(bsum);
    scan3_kernel<<<NBLK_SCAN, 256, 0, stream>>>(rowp, bsum);
    copy_rowp_kernel<<<NBLK_SCAN, 256, 0, stream>>>(rowp, curs);

    // --- two-level edge sort by dst ---
    part_count_kernel<<<gE, BT, 0, stream>>>(dst, bcnt);
    part_scan_kernel<<<NBUCK, 64, 0, stream>>>(bcnt, btot);
    bbase_scan_kernel<<<1, 1, 0, stream>>>(btot, bbase);
    part_scatter_kernel<<<gE, BT, 0, stream>>>(src, dst, bcnt, bbase, part);
    final_scatter_kernel<<<gE, BT, 0, stream>>>(part, dinv, curs, sedge);

    // --- conversions ---
    cvt_x_kernel<<<(int)(((long)N_NODES * 128 / 4 + BT - 1) / BT), BT, 0, stream>>>(x, P1);
    cvt_w_kernel<<<(128 * 256 + BT - 1) / BT, BT, 0, stream>>>(W1, Wt1, 128, 256);
    cvt_w_kernel<<<(256 * 128 + BT - 1) / BT, BT, 0, stream>>>(W2, Wt2, 256, 128);
    cvt_w_kernel<<<(128 * 64 + BT - 1) / BT, BT, 0, stream>>>(W3, Wt3, 128, 64);

    // --- layer 1: agg(x) [P1->P2], gemm 128->256 +b1 +relu [P2->P3] ---
    agg_csr_kernel<128, false, false, false, false><<<gAgg, BT, 0, stream>>>(
        P1, dinv, rowp, degi, sedge, nullptr, P2);
    {
        dim3 g(gRows, 4);
        gemm_mfma_kernel<128, 256, true, true><<<g, BT, 0, stream>>>(P2, Wt1, b1, P3, N_NODES);
    }

    // --- layer 2: gemm 256->128 [P3->P1], agg +b2 +relu [P1->P2] ---
    {
        dim3 g(gRows, 2);
        gemm_mfma_kernel<256, 128, false, false><<<g, BT, 0, stream>>>(P3, Wt2, nullptr, P1, N_NODES);
    }
    agg_csr_kernel<128, true, true, false, false><<<gAgg, BT, 0, stream>>>(
        P1, dinv, rowp, degi, sedge, b2, P2);

    // --- layer 3: gemm 128->64 [P2->P1], agg +b3 +relu +logsm [P1->out] ---
    {
        dim3 g(gRows, 1);
        gemm_mfma_kernel<128, 64, false, false><<<g, BT, 0, stream>>>(P2, Wt3, nullptr, P1, N_NODES);
    }
    agg_csr_kernel<64, true, true, true, true><<<gAgg, BT, 0, stream>>>(
        P1, dinv, rowp, degi, sedge, b3, out);

    (void)in_sizes; (void)n_in; (void)out_size; (void)ws_size;
}

// Round 7
// 506.847 us; speedup vs baseline: 2.0420x; 1.0336x over previous
//
#include <hip/hip_runtime.h>
#include <math.h>

#define N_NODES 100000
#define N_EDGES 1600000
#define NBLK_SCAN ((N_NODES + 255) / 256)   // 391
#define CHUNK 4096
#define NBLK_P ((N_EDGES + CHUNK - 1) / CHUNK)  // 391
#define NPAD 100064                          // 64-row padded for GEMM staging
#define NBUCK 25                             // dst>>12 buckets (4096 nodes each)

typedef __attribute__((ext_vector_type(8))) short bf16x8;
typedef __attribute__((ext_vector_type(4))) float f32x4;

__device__ __forceinline__ unsigned short f2bf(float f) {
    unsigned int u = __builtin_bit_cast(unsigned int, f);
    u += 0x7fffu + ((u >> 16) & 1u);          // RNE
    return (unsigned short)(u >> 16);
}
__device__ __forceinline__ float bflo2f(unsigned int u) {   // low 16 bits = bf16
    return __builtin_bit_cast(float, u << 16);
}
__device__ __forceinline__ float bfhi2f(unsigned int u) {   // high 16 bits = bf16
    return __builtin_bit_cast(float, u & 0xffff0000u);
}

// ---------------- fused degree + bucket count (reads dst ONCE) ----------------

__global__ void edge_count_kernel(const int* __restrict__ dst,
                                  int* degi, int* __restrict__ bcnt) {
    __shared__ int lh[NBUCK];
    int tid = threadIdx.x;
    if (tid < NBUCK) lh[tid] = 0;
    __syncthreads();
    long base = (long)blockIdx.x * CHUNK;
#pragma unroll
    for (int p = 0; p < CHUNK; p += 256) {
        long e = base + p + tid;
        if (e < N_EDGES) {
            int d = dst[e];
            atomicAdd(&degi[d], 1);
            atomicAdd(&lh[d >> 12], 1);
        }
    }
    __syncthreads();
    if (tid < NBUCK) bcnt[tid * NBLK_P + blockIdx.x] = lh[tid];
}

// ---------------- node exclusive scan (3-phase) + dinv + curs fused ----------------

__global__ void scan1_kernel(const int* __restrict__ deg, int* __restrict__ ex,
                             int* __restrict__ bsum, float* __restrict__ dinv) {
    __shared__ int tmp[256];
    int i = blockIdx.x * 256 + threadIdx.x;
    int v = (i < N_NODES) ? deg[i] : 0;
    if (i < N_NODES) dinv[i] = rsqrtf(1.0f + (float)v);  // +1 self-loop
    tmp[threadIdx.x] = v;
    __syncthreads();
    for (int off = 1; off < 256; off <<= 1) {
        int t = (threadIdx.x >= off) ? tmp[threadIdx.x - off] : 0;
        __syncthreads();
        tmp[threadIdx.x] += t;
        __syncthreads();
    }
    if (i < N_NODES) ex[i] = tmp[threadIdx.x] - v;
    if (threadIdx.x == 255) bsum[blockIdx.x] = tmp[255];
}

__global__ void scan2_kernel(int* bsum) {
    __shared__ int tmp[512];
    int i = threadIdx.x;
    int v = (i < NBLK_SCAN) ? bsum[i] : 0;
    tmp[i] = v;
    __syncthreads();
    for (int off = 1; off < 512; off <<= 1) {
        int t = (i >= off) ? tmp[i - off] : 0;
        __syncthreads();
        tmp[i] += t;
        __syncthreads();
    }
    if (i < NBLK_SCAN) bsum[i] = tmp[i] - v;
}

__global__ void scan3_kernel(int* rowptr, const int* __restrict__ bsum,
                             int* __restrict__ curs) {
    int i = blockIdx.x * 256 + threadIdx.x;
    if (i < N_NODES) {
        int r = rowptr[i] + bsum[blockIdx.x];
        rowptr[i] = r;
        curs[i] = r;
    }
}

// ---------------- bucket scan over blocks (one wave per bucket, 7 chunks) ----------------

__global__ void bucket_scan_kernel(int* __restrict__ bcnt, int* __restrict__ btot) {
    int bu = blockIdx.x, lane = threadIdx.x;   // 64 threads
    int base = 0;
    for (int i0 = 0; i0 < NBLK_P; i0 += 64) {
        int i = i0 + lane;
        int v = (i < NBLK_P) ? bcnt[bu * NBLK_P + i] : 0;
        int orig = v;
#pragma unroll
        for (int off = 1; off < 64; off <<= 1) {
            int t = __shfl_up(v, off);
            if (lane >= off) v += t;
        }
        if (i < NBLK_P) bcnt[bu * NBLK_P + i] = base + v - orig;
        base += __shfl(v, 63);
    }
    if (lane == 0) btot[bu] = base;
}

__global__ void bbase_scan_kernel(const int* __restrict__ btot, int* __restrict__ bbase) {
    int acc = 0;
    for (int i = 0; i < NBUCK; ++i) { bbase[i] = acc; acc += btot[i]; }
}

// ---------------- partition edges into bucket-contiguous (src,dst) records ----------------

__global__ void part_scatter_kernel(const int* __restrict__ src, const int* __restrict__ dst,
                                    const int* __restrict__ bcnt, const int* __restrict__ bbase,
                                    int2* __restrict__ part) {
    __shared__ int lh[NBUCK];
    int tid = threadIdx.x;
    if (tid < NBUCK) lh[tid] = 0;
    __syncthreads();
    long base = (long)blockIdx.x * CHUNK;
#pragma unroll
    for (int p = 0; p < CHUNK; p += 256) {
        long e = base + p + tid;
        if (e < N_EDGES) {
            int s = src[e], d = dst[e];
            int bu = d >> 12;
            int lr = atomicAdd(&lh[bu], 1);
            int pos = bbase[bu] + bcnt[bu * NBLK_P + blockIdx.x] + lr;
            int2 rec; rec.x = s; rec.y = d;
            part[pos] = rec;
        }
    }
}

// ---------------- final per-node scatter (src only; L2-resident 256KB windows) ----------------

__global__ void final_scatter_kernel(const int2* __restrict__ part,
                                     int* curs, int* __restrict__ ssrc) {
    int e = blockIdx.x * 256 + threadIdx.x;
    if (e >= N_EDGES) return;
    int2 r = part[e];
    int pos = atomicAdd(&curs[r.y], 1);   // curs pre-initialized to rowptr
    ssrc[pos] = r.x;
}

// ---------------- conversions ----------------

__global__ void cvt_x_kernel(const float* __restrict__ x, unsigned short* __restrict__ xb) {
    long i = (long)blockIdx.x * blockDim.x + threadIdx.x;   // over n/4
    if (i >= (long)N_NODES * 128 / 4) return;
    float4 v = ((const float4*)x)[i];
    ushort4 o;
    o.x = f2bf(v.x); o.y = f2bf(v.y); o.z = f2bf(v.z); o.w = f2bf(v.w);
    ((ushort4*)xb)[i] = o;
}

// all three weights, transposed+converted: Wt[m][k] = bf16(W[k][m])
__global__ void cvt_w_all_kernel(const float* __restrict__ W1, const float* __restrict__ W2,
                                 const float* __restrict__ W3,
                                 unsigned short* __restrict__ Wt1,
                                 unsigned short* __restrict__ Wt2,
                                 unsigned short* __restrict__ Wt3) {
    int i = blockIdx.x * blockDim.x + threadIdx.x;
    if (i < 32768) {                       // W1: [128][256]
        int k = i >> 8, m = i & 255;
        Wt1[m * 128 + k] = f2bf(W1[i]);
    } else if (i < 65536) {                // W2: [256][128]
        int j = i - 32768;
        int k = j >> 7, m = j & 127;
        Wt2[m * 256 + k] = f2bf(W2[j]);
    } else if (i < 73728) {                // W3: [128][64]
        int j = i - 65536;
        int k = j >> 6, m = j & 63;
        Wt3[m * 128 + k] = f2bf(W3[j]);
    }
}

// ---------------- CSR gather aggregation (bf16 in, bf16/f32 out) ----------------
// one 64-lane wave per dst node; lane owns C/64 channels; dinv[src] broadcast-read
template<int C, bool BIAS, bool RELU, bool LOGSM, bool OUTF32>
__global__ void agg_csr_kernel(const unsigned short* __restrict__ h,
                               const float* __restrict__ dinv,
                               const int* __restrict__ rowptr, const int* __restrict__ deg,
                               const int* __restrict__ ssrc,
                               const float* __restrict__ bias, void* __restrict__ outv) {
    constexpr int V = C / 64;  // 2 for C=128, 1 for C=64
    int gw = (int)((blockIdx.x * (long)blockDim.x + threadIdx.x) >> 6);
    int lane = threadIdx.x & 63;
    if (gw >= N_NODES) return;

    float di = dinv[gw];
    int st = rowptr[gw];
    int cnt = deg[gw];
    float a0, a1 = 0.0f;
    if constexpr (V == 2) {
        unsigned int u = ((const unsigned int*)(h + (long)gw * C))[lane];
        a0 = di * bflo2f(u); a1 = di * bfhi2f(u);
    } else {
        a0 = di * bflo2f(h[(long)gw * C + lane]);
    }

    int k = 0;
    for (; k + 4 <= cnt; k += 4) {
        int s0 = ssrc[st + k],     s1 = ssrc[st + k + 1];
        int s2 = ssrc[st + k + 2], s3 = ssrc[st + k + 3];
        float w0 = dinv[s0], w1 = dinv[s1], w2 = dinv[s2], w3 = dinv[s3];
        if constexpr (V == 2) {
            unsigned int u0 = ((const unsigned int*)(h + (long)s0 * C))[lane];
            unsigned int u1 = ((const unsigned int*)(h + (long)s1 * C))[lane];
            unsigned int u2 = ((const unsigned int*)(h + (long)s2 * C))[lane];
            unsigned int u3 = ((const unsigned int*)(h + (long)s3 * C))[lane];
            a0 += w0 * bflo2f(u0); a1 += w0 * bfhi2f(u0);
            a0 += w1 * bflo2f(u1); a1 += w1 * bfhi2f(u1);
            a0 += w2 * bflo2f(u2); a1 += w2 * bfhi2f(u2);
            a0 += w3 * bflo2f(u3); a1 += w3 * bfhi2f(u3);
        } else {
            a0 += w0 * bflo2f(h[(long)s0 * C + lane]);
            a0 += w1 * bflo2f(h[(long)s1 * C + lane]);
            a0 += w2 * bflo2f(h[(long)s2 * C + lane]);
            a0 += w3 * bflo2f(h[(long)s3 * C + lane]);
        }
    }
    for (; k < cnt; ++k) {
        int s = ssrc[st + k];
        float w = dinv[s];
        if constexpr (V == 2) {
            unsigned int u = ((const unsigned int*)(h + (long)s * C))[lane];
            a0 += w * bflo2f(u); a1 += w * bfhi2f(u);
        } else {
            a0 += w * bflo2f(h[(long)s * C + lane]);
        }
    }

    a0 *= di; a1 *= di;
    if constexpr (BIAS) {
        if constexpr (V == 2) { a0 += bias[lane * 2]; a1 += bias[lane * 2 + 1]; }
        else a0 += bias[lane];
    }
    if constexpr (RELU) { a0 = fmaxf(a0, 0.0f); a1 = fmaxf(a1, 0.0f); }
    if constexpr (LOGSM) {  // V==1 only
        float m = a0;
#pragma unroll
        for (int o = 32; o > 0; o >>= 1) m = fmaxf(m, __shfl_xor(m, o));
        float e = expf(a0 - m), s = e;
#pragma unroll
        for (int o = 32; o > 0; o >>= 1) s += __shfl_xor(s, o);
        a0 = a0 - m - logf(s);
    }
    if constexpr (OUTF32) {
        float* out = (float*)outv;
        if constexpr (V == 2) {
            float2 r; r.x = a0; r.y = a1;
            *(float2*)(out + (long)gw * C + lane * 2) = r;
        } else {
            out[(long)gw * C + lane] = a0;
        }
    } else {
        unsigned short* out = (unsigned short*)outv;
        if constexpr (V == 2) {
            unsigned int up = (unsigned int)f2bf(a0) | ((unsigned int)f2bf(a1) << 16);
            ((unsigned int*)(out + (long)gw * C))[lane] = up;
        } else {
            out[(long)gw * C + lane] = f2bf(a0);
        }
    }
}

// ---------------- bf16 MFMA GEMM ----------------
// C[N,M](bf16) = A[N,K](bf16) @ Wt[M,K]^T (+bias)(relu)
// 64x64 block tile, 4 waves 2x2, each wave 32x32 via mfma_f32_16x16x32_bf16.
template<int K, int M, bool BIAS, bool RELU>
__global__ __launch_bounds__(256) void gemm_mfma_kernel(
        const unsigned short* __restrict__ A,   // [NPAD][K]
        const unsigned short* __restrict__ Bt,  // [M][K]
        const float* __restrict__ bias,         // [M]
        unsigned short* __restrict__ Cb,        // [NPAD][M]
        int N) {
    constexpr int KC = K / 8;                    // 16B chunks per row
    __shared__ unsigned short As[64 * K];
    __shared__ unsigned short Bs[64 * K];

    int tid = threadIdx.x;
    int row0 = blockIdx.x * 64;
    int col0 = blockIdx.y * 64;

    const unsigned short* Ap = A + (long)row0 * K;
    const unsigned short* Bp = Bt + (long)col0 * K;

    // stage both panels; LDS byte = (c*16) ^ ((row&7)<<4)
    for (int c = tid; c < 64 * KC; c += 256) {
        int r = c / KC;
        unsigned int swz = ((unsigned int)c * 16u) ^ ((unsigned int)(r & 7) << 4);
        bf16x8 va = *(const bf16x8*)(Ap + c * 8);
        bf16x8 vb = *(const bf16x8*)(Bp + c * 8);
        *(bf16x8*)((char*)As + swz) = va;
        *(bf16x8*)((char*)Bs + swz) = vb;
    }
    __syncthreads();

    int lane = tid & 63;
    int wv = tid >> 6;
    int wr = wv >> 1, wc = wv & 1;      // wave tile origin (wr*32, wc*32)
    int lr = lane & 15;
    int kg = lane >> 4;                 // k-group: k = kg*8 + j

    f32x4 acc[2][2] = {};

    for (int k0 = 0; k0 < K; k0 += 32) {
        bf16x8 a[2], b[2];
#pragma unroll
        for (int mi = 0; mi < 2; ++mi) {
            int r = wr * 32 + mi * 16 + lr;
            unsigned int byteo = (unsigned int)((r * K + k0 + kg * 8) * 2);
            byteo ^= (unsigned int)((r & 7) << 4);
            a[mi] = *(const bf16x8*)((const char*)As + byteo);
        }
#pragma unroll
        for (int ni = 0; ni < 2; ++ni) {
            int r = wc * 32 + ni * 16 + lr;
            unsigned int byteo = (unsigned int)((r * K + k0 + kg * 8) * 2);
            byteo ^= (unsigned int)((r & 7) << 4);
            b[ni] = *(const bf16x8*)((const char*)Bs + byteo);
        }
#pragma unroll
        for (int mi = 0; mi < 2; ++mi)
#pragma unroll
            for (int ni = 0; ni < 2; ++ni)
                acc[mi][ni] = __builtin_amdgcn_mfma_f32_16x16x32_bf16(
                    a[mi], b[ni], acc[mi][ni], 0, 0, 0);
    }

    // epilogue: C/D layout col=lane&15, row=(lane>>4)*4+i
#pragma unroll
    for (int mi = 0; mi < 2; ++mi) {
#pragma unroll
        for (int ni = 0; ni < 2; ++ni) {
            int col = col0 + wc * 32 + ni * 16 + lr;
            float bv = BIAS ? bias[col] : 0.0f;
#pragma unroll
            for (int i = 0; i < 4; ++i) {
                int row = row0 + wr * 32 + mi * 16 + kg * 4 + i;
                if (row < N) {
                    float v = acc[mi][ni][i] + bv;
                    if (RELU) v = fmaxf(v, 0.0f);
                    Cb[(long)row * M + col] = f2bf(v);
                }
            }
        }
    }
}

// ---------------- launch ----------------

extern "C" void kernel_launch(void* const* d_in, const int* in_sizes, int n_in,
                              void* d_out, int out_size, void* d_ws, size_t ws_size,
                              hipStream_t stream) {
    const float* x  = (const float*)d_in[0];
    const int* edge = (const int*)d_in[1];
    const float* W1 = (const float*)d_in[2];
    const float* b1 = (const float*)d_in[3];
    const float* W2 = (const float*)d_in[4];
    const float* b2 = (const float*)d_in[5];
    const float* W3 = (const float*)d_in[6];
    const float* b3 = (const float*)d_in[7];
    float* out = (float*)d_out;

    const int* src = edge;
    const int* dst = edge + N_EDGES;

    // workspace layout (float-element offsets)
    float* ws    = (float*)d_ws;
    float* dinv  = ws;                                   // [0,      100000)
    int*   degi  = (int*)(ws + 100000);                  // N
    int*   rowp  = (int*)(ws + 200000);                  // N
    int*   curs  = (int*)(ws + 300000);                  // N
    int*   bsum  = (int*)(ws + 400000);                  // 391 (alloc 512)
    int*   btot  = (int*)(ws + 400512);                  // 25 (alloc 32)
    int*   bbase = (int*)(ws + 400544);                  // 25 (alloc 32)
    int*   bcnt  = (int*)(ws + 400576);                  // NBUCK*NBLK_P = 9775 (alloc 10000)
    int*   ssrc  = (int*)(ws + 410576);                  // E ints
    unsigned short* P1  = (unsigned short*)(ws + 2010576);   // [NPAD][128]
    unsigned short* P2  = P1 + (size_t)NPAD * 128;           // [NPAD][128]
    unsigned short* P3  = P2 + (size_t)NPAD * 128;           // [NPAD][256]
    unsigned short* Wt1 = P3 + (size_t)NPAD * 256;           // [256][128]
    unsigned short* Wt2 = Wt1 + 128 * 256;                   // [128][256]
    unsigned short* Wt3 = Wt2 + 256 * 128;                   // [64][128]
    int2*  part  = (int2*)P3;   // scratch reuse: consumed before gemm1 writes P3

    const int BT = 256;
    int gAgg = (int)(((long)N_NODES * 64 + BT - 1) / BT);
    int gRows = (N_NODES + 63) / 64;   // 1563

    // --- fused degree + bucket counts (reads dst once) ---
    hipMemsetAsync(degi, 0, N_NODES * sizeof(int), stream);
    edge_count_kernel<<<NBLK_P, BT, 0, stream>>>(dst, degi, bcnt);

    // --- node scan (+dinv, +curs) ---
    scan1_kernel<<<NBLK_SCAN, 256, 0, stream>>>(degi, rowp, bsum, dinv);
    scan2_kernel<<<1, 512, 0, stream>>>(bsum);
    scan3_kernel<<<NBLK_SCAN, 256, 0, stream>>>(rowp, bsum, curs);

    // --- bucket scan + partition + final scatter ---
    bucket_scan_kernel<<<NBUCK, 64, 0, stream>>>(bcnt, btot);
    bbase_scan_kernel<<<1, 1, 0, stream>>>(btot, bbase);
    part_scatter_kernel<<<NBLK_P, BT, 0, stream>>>(src, dst, bcnt, bbase, part);
    final_scatter_kernel<<<(N_EDGES + BT - 1) / BT, BT, 0, stream>>>(part, curs, ssrc);

    // --- conversions ---
    cvt_x_kernel<<<(int)(((long)N_NODES * 128 / 4 + BT - 1) / BT), BT, 0, stream>>>(x, P1);
    cvt_w_all_kernel<<<(73728 + BT - 1) / BT, BT, 0, stream>>>(W1, W2, W3, Wt1, Wt2, Wt3);

    // --- layer 1: agg(x) [P1->P2], gemm 128->256 +b1 +relu [P2->P3] ---
    agg_csr_kernel<128, false, false, false, false><<<gAgg, BT, 0, stream>>>(
        P1, dinv, rowp, degi, ssrc, nullptr, P2);
    {
        dim3 g(gRows, 4);
        gemm_mfma_kernel<128, 256, true, true><<<g, BT, 0, stream>>>(P2, Wt1, b1, P3, N_NODES);
    }

    // --- layer 2: gemm 256->128 [P3->P1], agg +b2 +relu [P1->P2] ---
    {
        dim3 g(gRows, 2);
        gemm_mfma_kernel<256, 128, false, false><<<g, BT, 0, stream>>>(P3, Wt2, nullptr, P1, N_NODES);
    }
    agg_csr_kernel<128, true, true, false, false><<<gAgg, BT, 0, stream>>>(
        P1, dinv, rowp, degi, ssrc, b2, P2);

    // --- layer 3: gemm 128->64 [P2->P1], agg +b3 +relu +logsm [P1->out] ---
    {
        dim3 g(gRows, 1);
        gemm_mfma_kernel<128, 64, false, false><<<g, BT, 0, stream>>>(P2, Wt3, nullptr, P1, N_NODES);
    }
    agg_csr_kernel<64, true, true, true, true><<<gAgg, BT, 0, stream>>>(
        P1, dinv, rowp, degi, ssrc, b3, out);

    (void)in_sizes; (void)n_in; (void)out_size; (void)ws_size;
}

// Round 8
// 449.254 us; speedup vs baseline: 2.3037x; 1.1282x over previous
//
#include <hip/hip_runtime.h>
#include <math.h>

#define N_NODES 100000
#define N_EDGES 1600000
#define NBLK_SCAN ((N_NODES + 255) / 256)   // 391
#define CHUNK 4096
#define NBLK_P ((N_EDGES + CHUNK - 1) / CHUNK)  // 391
#define NPAD 100064                          // 64-row padded for GEMM staging
#define NBUCK 25                             // dst>>12 buckets (4096 nodes each)

typedef __attribute__((ext_vector_type(8))) short bf16x8;
typedef __attribute__((ext_vector_type(4))) float f32x4;

__device__ __forceinline__ unsigned short f2bf(float f) {
    unsigned int u = __builtin_bit_cast(unsigned int, f);
    u += 0x7fffu + ((u >> 16) & 1u);          // RNE
    return (unsigned short)(u >> 16);
}
__device__ __forceinline__ float bflo2f(unsigned int u) {   // low 16 bits = bf16
    return __builtin_bit_cast(float, u << 16);
}
__device__ __forceinline__ float bfhi2f(unsigned int u) {   // high 16 bits = bf16
    return __builtin_bit_cast(float, u & 0xffff0000u);
}

// ---------------- fused degree + bucket count (reads dst ONCE) ----------------

__global__ void edge_count_kernel(const int* __restrict__ dst,
                                  int* degi, int* __restrict__ bcnt) {
    __shared__ int lh[NBUCK];
    int tid = threadIdx.x;
    if (tid < NBUCK) lh[tid] = 0;
    __syncthreads();
    long base = (long)blockIdx.x * CHUNK;
#pragma unroll
    for (int p = 0; p < CHUNK; p += 256) {
        long e = base + p + tid;
        if (e < N_EDGES) {
            int d = dst[e];
            atomicAdd(&degi[d], 1);
            atomicAdd(&lh[d >> 12], 1);
        }
    }
    __syncthreads();
    if (tid < NBUCK) bcnt[tid * NBLK_P + blockIdx.x] = lh[tid];
}

// ---------------- node exclusive scan (3-phase) + dinv + curs fused ----------------

__global__ void scan1_kernel(const int* __restrict__ deg, int* __restrict__ ex,
                             int* __restrict__ bsum, float* __restrict__ dinv) {
    __shared__ int tmp[256];
    int i = blockIdx.x * 256 + threadIdx.x;
    int v = (i < N_NODES) ? deg[i] : 0;
    if (i < N_NODES) dinv[i] = rsqrtf(1.0f + (float)v);  // +1 self-loop
    tmp[threadIdx.x] = v;
    __syncthreads();
    for (int off = 1; off < 256; off <<= 1) {
        int t = (threadIdx.x >= off) ? tmp[threadIdx.x - off] : 0;
        __syncthreads();
        tmp[threadIdx.x] += t;
        __syncthreads();
    }
    if (i < N_NODES) ex[i] = tmp[threadIdx.x] - v;
    if (threadIdx.x == 255) bsum[blockIdx.x] = tmp[255];
}

__global__ void scan2_kernel(int* bsum) {
    __shared__ int tmp[512];
    int i = threadIdx.x;
    int v = (i < NBLK_SCAN) ? bsum[i] : 0;
    tmp[i] = v;
    __syncthreads();
    for (int off = 1; off < 512; off <<= 1) {
        int t = (i >= off) ? tmp[i - off] : 0;
        __syncthreads();
        tmp[i] += t;
        __syncthreads();
    }
    if (i < NBLK_SCAN) bsum[i] = tmp[i] - v;
}

__global__ void scan3_kernel(int* rowptr, const int* __restrict__ bsum,
                             int* __restrict__ curs) {
    int i = blockIdx.x * 256 + threadIdx.x;
    if (i < N_NODES) {
        int r = rowptr[i] + bsum[blockIdx.x];
        rowptr[i] = r;
        curs[i] = r;
    }
}

// ---------------- bucket scan over blocks (one wave per bucket) ----------------

__global__ void bucket_scan_kernel(int* __restrict__ bcnt, int* __restrict__ btot) {
    int bu = blockIdx.x, lane = threadIdx.x;   // 64 threads
    int base = 0;
    for (int i0 = 0; i0 < NBLK_P; i0 += 64) {
        int i = i0 + lane;
        int v = (i < NBLK_P) ? bcnt[bu * NBLK_P + i] : 0;
        int orig = v;
#pragma unroll
        for (int off = 1; off < 64; off <<= 1) {
            int t = __shfl_up(v, off);
            if (lane >= off) v += t;
        }
        if (i < NBLK_P) bcnt[bu * NBLK_P + i] = base + v - orig;
        base += __shfl(v, 63);
    }
    if (lane == 0) btot[bu] = base;
}

__global__ void bbase_scan_kernel(const int* __restrict__ btot, int* __restrict__ bbase) {
    int acc = 0;
    for (int i = 0; i < NBUCK; ++i) { bbase[i] = acc; acc += btot[i]; }
}

// ---------------- partition edges into bucket-contiguous (src,dst) records ----------------

__global__ void part_scatter_kernel(const int* __restrict__ src, const int* __restrict__ dst,
                                    const int* __restrict__ bcnt, const int* __restrict__ bbase,
                                    int2* __restrict__ part) {
    __shared__ int lh[NBUCK];
    int tid = threadIdx.x;
    if (tid < NBUCK) lh[tid] = 0;
    __syncthreads();
    long base = (long)blockIdx.x * CHUNK;
#pragma unroll
    for (int p = 0; p < CHUNK; p += 256) {
        long e = base + p + tid;
        if (e < N_EDGES) {
            int s = src[e], d = dst[e];
            int bu = d >> 12;
            int lr = atomicAdd(&lh[bu], 1);
            int pos = bbase[bu] + bcnt[bu * NBLK_P + blockIdx.x] + lr;
            int2 rec; rec.x = s; rec.y = d;
            part[pos] = rec;
        }
    }
}

// ---------------- final per-node scatter (embed dinv[src]; L2-resident windows) ----------------

__global__ void final_scatter_kernel(const int2* __restrict__ part,
                                     const float* __restrict__ dinv,
                                     int* curs, int2* __restrict__ sedge) {
    int e = blockIdx.x * 256 + threadIdx.x;
    if (e >= N_EDGES) return;
    int2 r = part[e];
    int pos = atomicAdd(&curs[r.y], 1);   // curs pre-initialized to rowptr
    int2 rec; rec.x = r.x; rec.y = __float_as_int(dinv[r.x]);
    sedge[pos] = rec;
}

// ---------------- conversions ----------------

__global__ void cvt_x_kernel(const float* __restrict__ x, unsigned short* __restrict__ xb) {
    long i = (long)blockIdx.x * blockDim.x + threadIdx.x;   // over n/4
    if (i >= (long)N_NODES * 128 / 4) return;
    float4 v = ((const float4*)x)[i];
    ushort4 o;
    o.x = f2bf(v.x); o.y = f2bf(v.y); o.z = f2bf(v.z); o.w = f2bf(v.w);
    ((ushort4*)xb)[i] = o;
}

// all three weights, transposed+converted: Wt[m][k] = bf16(W[k][m])
__global__ void cvt_w_all_kernel(const float* __restrict__ W1, const float* __restrict__ W2,
                                 const float* __restrict__ W3,
                                 unsigned short* __restrict__ Wt1,
                                 unsigned short* __restrict__ Wt2,
                                 unsigned short* __restrict__ Wt3) {
    int i = blockIdx.x * blockDim.x + threadIdx.x;
    if (i < 32768) {                       // W1: [128][256]
        int k = i >> 8, m = i & 255;
        Wt1[m * 128 + k] = f2bf(W1[i]);
    } else if (i < 65536) {                // W2: [256][128]
        int j = i - 32768;
        int k = j >> 7, m = j & 127;
        Wt2[m * 256 + k] = f2bf(W2[j]);
    } else if (i < 73728) {                // W3: [128][64]
        int j = i - 65536;
        int k = j >> 6, m = j & 63;
        Wt3[m * 128 + k] = f2bf(W3[j]);
    }
}

// ---------------- CSR gather aggregation (bf16 in, bf16/f32 out) ----------------
// one 64-lane wave per dst node; lane owns C/64 channels; 8 gathers in flight
template<int C, bool BIAS, bool RELU, bool LOGSM, bool OUTF32>
__global__ void agg_csr_kernel(const unsigned short* __restrict__ h,
                               const float* __restrict__ dinv,
                               const int* __restrict__ rowptr, const int* __restrict__ deg,
                               const int2* __restrict__ sedge,
                               const float* __restrict__ bias, void* __restrict__ outv) {
    constexpr int V = C / 64;  // 2 for C=128, 1 for C=64
    int gw = (int)((blockIdx.x * (long)blockDim.x + threadIdx.x) >> 6);
    int lane = threadIdx.x & 63;
    if (gw >= N_NODES) return;

    float di = dinv[gw];
    int st = rowptr[gw];
    int cnt = deg[gw];
    float a0, a1 = 0.0f;
    if constexpr (V == 2) {
        unsigned int u = ((const unsigned int*)(h + (long)gw * C))[lane];
        a0 = di * bflo2f(u); a1 = di * bfhi2f(u);
    } else {
        a0 = di * bflo2f(h[(long)gw * C + lane]);
    }

    int k = 0;
    // 8-deep gather block
    for (; k + 8 <= cnt; k += 8) {
        int2 r[8];
#pragma unroll
        for (int j = 0; j < 8; ++j) r[j] = sedge[st + k + j];
        if constexpr (V == 2) {
            unsigned int u[8];
#pragma unroll
            for (int j = 0; j < 8; ++j)
                u[j] = ((const unsigned int*)(h + (long)r[j].x * C))[lane];
#pragma unroll
            for (int j = 0; j < 8; ++j) {
                float w = __int_as_float(r[j].y);
                a0 += w * bflo2f(u[j]); a1 += w * bfhi2f(u[j]);
            }
        } else {
            unsigned short u[8];
#pragma unroll
            for (int j = 0; j < 8; ++j)
                u[j] = h[(long)r[j].x * C + lane];
#pragma unroll
            for (int j = 0; j < 8; ++j)
                a0 += __int_as_float(r[j].y) * bflo2f(u[j]);
        }
    }
    // 4-deep
    for (; k + 4 <= cnt; k += 4) {
        int2 r[4];
#pragma unroll
        for (int j = 0; j < 4; ++j) r[j] = sedge[st + k + j];
        if constexpr (V == 2) {
            unsigned int u[4];
#pragma unroll
            for (int j = 0; j < 4; ++j)
                u[j] = ((const unsigned int*)(h + (long)r[j].x * C))[lane];
#pragma unroll
            for (int j = 0; j < 4; ++j) {
                float w = __int_as_float(r[j].y);
                a0 += w * bflo2f(u[j]); a1 += w * bfhi2f(u[j]);
            }
        } else {
            unsigned short u[4];
#pragma unroll
            for (int j = 0; j < 4; ++j)
                u[j] = h[(long)r[j].x * C + lane];
#pragma unroll
            for (int j = 0; j < 4; ++j)
                a0 += __int_as_float(r[j].y) * bflo2f(u[j]);
        }
    }
    // tail
    for (; k < cnt; ++k) {
        int2 r = sedge[st + k];
        float w = __int_as_float(r.y);
        if constexpr (V == 2) {
            unsigned int u = ((const unsigned int*)(h + (long)r.x * C))[lane];
            a0 += w * bflo2f(u); a1 += w * bfhi2f(u);
        } else {
            a0 += w * bflo2f(h[(long)r.x * C + lane]);
        }
    }

    a0 *= di; a1 *= di;
    if constexpr (BIAS) {
        if constexpr (V == 2) { a0 += bias[lane * 2]; a1 += bias[lane * 2 + 1]; }
        else a0 += bias[lane];
    }
    if constexpr (RELU) { a0 = fmaxf(a0, 0.0f); a1 = fmaxf(a1, 0.0f); }
    if constexpr (LOGSM) {  // V==1 only
        float m = a0;
#pragma unroll
        for (int o = 32; o > 0; o >>= 1) m = fmaxf(m, __shfl_xor(m, o));
        float e = expf(a0 - m), s = e;
#pragma unroll
        for (int o = 32; o > 0; o >>= 1) s += __shfl_xor(s, o);
        a0 = a0 - m - logf(s);
    }
    if constexpr (OUTF32) {
        float* out = (float*)outv;
        if constexpr (V == 2) {
            float2 r; r.x = a0; r.y = a1;
            *(float2*)(out + (long)gw * C + lane * 2) = r;
        } else {
            out[(long)gw * C + lane] = a0;
        }
    } else {
        unsigned short* out = (unsigned short*)outv;
        if constexpr (V == 2) {
            unsigned int up = (unsigned int)f2bf(a0) | ((unsigned int)f2bf(a1) << 16);
            ((unsigned int*)(out + (long)gw * C))[lane] = up;
        } else {
            out[(long)gw * C + lane] = f2bf(a0);
        }
    }
}

// ---------------- bf16 MFMA GEMM ----------------
// C[N,M](bf16) = A[N,K](bf16) @ Wt[M,K]^T (+bias)(relu)
// 64x64 block tile, 4 waves 2x2, each wave 32x32 via mfma_f32_16x16x32_bf16.
template<int K, int M, bool BIAS, bool RELU>
__global__ __launch_bounds__(256) void gemm_mfma_kernel(
        const unsigned short* __restrict__ A,   // [NPAD][K]
        const unsigned short* __restrict__ Bt,  // [M][K]
        const float* __restrict__ bias,         // [M]
        unsigned short* __restrict__ Cb,        // [NPAD][M]
        int N) {
    constexpr int KC = K / 8;                    // 16B chunks per row
    __shared__ unsigned short As[64 * K];
    __shared__ unsigned short Bs[64 * K];

    int tid = threadIdx.x;
    int row0 = blockIdx.x * 64;
    int col0 = blockIdx.y * 64;

    const unsigned short* Ap = A + (long)row0 * K;
    const unsigned short* Bp = Bt + (long)col0 * K;

    // stage both panels; LDS byte = (c*16) ^ ((row&7)<<4)
    for (int c = tid; c < 64 * KC; c += 256) {
        int r = c / KC;
        unsigned int swz = ((unsigned int)c * 16u) ^ ((unsigned int)(r & 7) << 4);
        bf16x8 va = *(const bf16x8*)(Ap + c * 8);
        bf16x8 vb = *(const bf16x8*)(Bp + c * 8);
        *(bf16x8*)((char*)As + swz) = va;
        *(bf16x8*)((char*)Bs + swz) = vb;
    }
    __syncthreads();

    int lane = tid & 63;
    int wv = tid >> 6;
    int wr = wv >> 1, wc = wv & 1;      // wave tile origin (wr*32, wc*32)
    int lr = lane & 15;
    int kg = lane >> 4;                 // k-group: k = kg*8 + j

    f32x4 acc[2][2] = {};

    for (int k0 = 0; k0 < K; k0 += 32) {
        bf16x8 a[2], b[2];
#pragma unroll
        for (int mi = 0; mi < 2; ++mi) {
            int r = wr * 32 + mi * 16 + lr;
            unsigned int byteo = (unsigned int)((r * K + k0 + kg * 8) * 2);
            byteo ^= (unsigned int)((r & 7) << 4);
            a[mi] = *(const bf16x8*)((const char*)As + byteo);
        }
#pragma unroll
        for (int ni = 0; ni < 2; ++ni) {
            int r = wc * 32 + ni * 16 + lr;
            unsigned int byteo = (unsigned int)((r * K + k0 + kg * 8) * 2);
            byteo ^= (unsigned int)((r & 7) << 4);
            b[ni] = *(const bf16x8*)((const char*)Bs + byteo);
        }
#pragma unroll
        for (int mi = 0; mi < 2; ++mi)
#pragma unroll
            for (int ni = 0; ni < 2; ++ni)
                acc[mi][ni] = __builtin_amdgcn_mfma_f32_16x16x32_bf16(
                    a[mi], b[ni], acc[mi][ni], 0, 0, 0);
    }

    // epilogue: C/D layout col=lane&15, row=(lane>>4)*4+i
#pragma unroll
    for (int mi = 0; mi < 2; ++mi) {
#pragma unroll
        for (int ni = 0; ni < 2; ++ni) {
            int col = col0 + wc * 32 + ni * 16 + lr;
            float bv = BIAS ? bias[col] : 0.0f;
#pragma unroll
            for (int i = 0; i < 4; ++i) {
                int row = row0 + wr * 32 + mi * 16 + kg * 4 + i;
                if (row < N) {
                    float v = acc[mi][ni][i] + bv;
                    if (RELU) v = fmaxf(v, 0.0f);
                    Cb[(long)row * M + col] = f2bf(v);
                }
            }
        }
    }
}

// ---------------- launch ----------------

extern "C" void kernel_launch(void* const* d_in, const int* in_sizes, int n_in,
                              void* d_out, int out_size, void* d_ws, size_t ws_size,
                              hipStream_t stream) {
    const float* x  = (const float*)d_in[0];
    const int* edge = (const int*)d_in[1];
    const float* W1 = (const float*)d_in[2];
    const float* b1 = (const float*)d_in[3];
    const float* W2 = (const float*)d_in[4];
    const float* b2 = (const float*)d_in[5];
    const float* W3 = (const float*)d_in[6];
    const float* b3 = (const float*)d_in[7];
    float* out = (float*)d_out;

    const int* src = edge;
    const int* dst = edge + N_EDGES;

    // workspace layout (float-element offsets)
    float* ws    = (float*)d_ws;
    float* dinv  = ws;                                   // N
    int*   degi  = (int*)(ws + 100000);                  // N
    int*   rowp  = (int*)(ws + 200000);                  // N
    int*   curs  = (int*)(ws + 300000);                  // N
    int*   bsum  = (int*)(ws + 400000);                  // 391 (alloc 512)
    int*   btot  = (int*)(ws + 400512);                  // 25 (alloc 32)
    int*   bbase = (int*)(ws + 400544);                  // 25 (alloc 32)
    int*   bcnt  = (int*)(ws + 400576);                  // 9775 (alloc 10016)
    int2*  sedge = (int2*)(ws + 410592);                 // E*2 ints (8B aligned)
    unsigned short* P1  = (unsigned short*)(ws + 3610592);   // [NPAD][128]
    unsigned short* P2  = P1 + (size_t)NPAD * 128;           // [NPAD][128]
    unsigned short* P3  = P2 + (size_t)NPAD * 128;           // [NPAD][256]
    unsigned short* Wt1 = P3 + (size_t)NPAD * 256;           // [256][128]
    unsigned short* Wt2 = Wt1 + 128 * 256;                   // [128][256]
    unsigned short* Wt3 = Wt2 + 256 * 128;                   // [64][128]
    int2*  part  = (int2*)P3;   // scratch reuse: consumed before gemm1 writes P3

    const int BT = 256;
    int gAgg = (int)(((long)N_NODES * 64 + BT - 1) / BT);
    int gRows = (N_NODES + 63) / 64;   // 1563

    // --- fused degree + bucket counts (reads dst once) ---
    hipMemsetAsync(degi, 0, N_NODES * sizeof(int), stream);
    edge_count_kernel<<<NBLK_P, BT, 0, stream>>>(dst, degi, bcnt);

    // --- node scan (+dinv, +curs) ---
    scan1_kernel<<<NBLK_SCAN, 256, 0, stream>>>(degi, rowp, bsum, dinv);
    scan2_kernel<<<1, 512, 0, stream>>>(bsum);
    scan3_kernel<<<NBLK_SCAN, 256, 0, stream>>>(rowp, bsum, curs);

    // --- bucket scan + partition + final scatter ---
    bucket_scan_kernel<<<NBUCK, 64, 0, stream>>>(bcnt, btot);
    bbase_scan_kernel<<<1, 1, 0, stream>>>(btot, bbase);
    part_scatter_kernel<<<NBLK_P, BT, 0, stream>>>(src, dst, bcnt, bbase, part);
    final_scatter_kernel<<<(N_EDGES + BT - 1) / BT, BT, 0, stream>>>(part, dinv, curs, sedge);

    // --- conversions ---
    cvt_x_kernel<<<(int)(((long)N_NODES * 128 / 4 + BT - 1) / BT), BT, 0, stream>>>(x, P1);
    cvt_w_all_kernel<<<(73728 + BT - 1) / BT, BT, 0, stream>>>(W1, W2, W3, Wt1, Wt2, Wt3);

    // --- layer 1: agg(x) [P1->P2], gemm 128->256 +b1 +relu [P2->P3] ---
    agg_csr_kernel<128, false, false, false, false><<<gAgg, BT, 0, stream>>>(
        P1, dinv, rowp, degi, sedge, nullptr, P2);
    {
        dim3 g(gRows, 4);
        gemm_mfma_kernel<128, 256, true, true><<<g, BT, 0, stream>>>(P2, Wt1, b1, P3, N_NODES);
    }

    // --- layer 2: gemm 256->128 [P3->P1], agg +b2 +relu [P1->P2] ---
    {
        dim3 g(gRows, 2);
        gemm_mfma_kernel<256, 128, false, false><<<g, BT, 0, stream>>>(P3, Wt2, nullptr, P1, N_NODES);
    }
    agg_csr_kernel<128, true, true, false, false><<<gAgg, BT, 0, stream>>>(
        P1, dinv, rowp, degi, sedge, b2, P2);

    // --- layer 3: gemm 128->64 [P2->P1], agg +b3 +relu +logsm [P1->out] ---
    {
        dim3 g(gRows, 1);
        gemm_mfma_kernel<128, 64, false, false><<<g, BT, 0, stream>>>(P2, Wt3, nullptr, P1, N_NODES);
    }
    agg_csr_kernel<64, true, true, true, true><<<gAgg, BT, 0, stream>>>(
        P1, dinv, rowp, degi, sedge, b3, out);

    (void)in_sizes; (void)n_in; (void)out_size; (void)ws_size;
}

// Round 9
// 410.489 us; speedup vs baseline: 2.5213x; 1.0944x over previous
//
#include <hip/hip_runtime.h>
#include <math.h>

#define N_NODES 100000
#define N_EDGES 1600000
#define NBLK_SCAN ((N_NODES + 255) / 256)   // 391
#define CHUNK 4096
#define NBLK_P ((N_EDGES + CHUNK - 1) / CHUNK)  // 391
#define NPAD 100064                          // 64-row padded for GEMM staging
#define BSHIFT 8                             // 256 nodes per bucket
#define NBUCK ((N_NODES + 255) / 256)        // 391 buckets
#define BCAP 6144                            // LDS record capacity per bucket

typedef __attribute__((ext_vector_type(8))) short bf16x8;
typedef __attribute__((ext_vector_type(4))) float f32x4;

__device__ __forceinline__ unsigned short f2bf(float f) {
    unsigned int u = __builtin_bit_cast(unsigned int, f);
    u += 0x7fffu + ((u >> 16) & 1u);          // RNE
    return (unsigned short)(u >> 16);
}
__device__ __forceinline__ float bflo2f(unsigned int u) {   // low 16 bits = bf16
    return __builtin_bit_cast(float, u << 16);
}
__device__ __forceinline__ float bfhi2f(unsigned int u) {   // high 16 bits = bf16
    return __builtin_bit_cast(float, u & 0xffff0000u);
}

// ---------------- fused degree + bucket count (reads dst ONCE) ----------------

__global__ void edge_count_kernel(const int* __restrict__ dst,
                                  int* degi, int* __restrict__ bcnt) {
    __shared__ int lh[NBUCK];
    int tid = threadIdx.x;
    for (int i = tid; i < NBUCK; i += 256) lh[i] = 0;
    __syncthreads();
    long base = (long)blockIdx.x * CHUNK;
#pragma unroll
    for (int p = 0; p < CHUNK; p += 256) {
        long e = base + p + tid;
        if (e < N_EDGES) {
            int d = dst[e];
            atomicAdd(&degi[d], 1);
            atomicAdd(&lh[d >> BSHIFT], 1);
        }
    }
    __syncthreads();
    for (int i = tid; i < NBUCK; i += 256)
        bcnt[i * NBLK_P + blockIdx.x] = lh[i];
}

// ---------------- node exclusive scan (3-phase) + dinv fused ----------------

__global__ void scan1_kernel(const int* __restrict__ deg, int* __restrict__ ex,
                             int* __restrict__ bsum, float* __restrict__ dinv) {
    __shared__ int tmp[256];
    int i = blockIdx.x * 256 + threadIdx.x;
    int v = (i < N_NODES) ? deg[i] : 0;
    if (i < N_NODES) dinv[i] = rsqrtf(1.0f + (float)v);  // +1 self-loop
    tmp[threadIdx.x] = v;
    __syncthreads();
    for (int off = 1; off < 256; off <<= 1) {
        int t = (threadIdx.x >= off) ? tmp[threadIdx.x - off] : 0;
        __syncthreads();
        tmp[threadIdx.x] += t;
        __syncthreads();
    }
    if (i < N_NODES) ex[i] = tmp[threadIdx.x] - v;
    if (threadIdx.x == 255) bsum[blockIdx.x] = tmp[255];
}

__global__ void scan2_kernel(int* bsum) {
    __shared__ int tmp[512];
    int i = threadIdx.x;
    int v = (i < NBLK_SCAN) ? bsum[i] : 0;
    tmp[i] = v;
    __syncthreads();
    for (int off = 1; off < 512; off <<= 1) {
        int t = (i >= off) ? tmp[i - off] : 0;
        __syncthreads();
        tmp[i] += t;
        __syncthreads();
    }
    if (i < NBLK_SCAN) bsum[i] = tmp[i] - v;
}

__global__ void scan3_kernel(int* rowptr, const int* __restrict__ bsum) {
    int i = blockIdx.x * 256 + threadIdx.x;
    if (i < N_NODES) rowptr[i] += bsum[blockIdx.x];
}

// ---------------- bucket scan over blocks (one wave per bucket) ----------------

__global__ void bucket_scan_kernel(int* __restrict__ bcnt, int* __restrict__ btot) {
    int bu = blockIdx.x, lane = threadIdx.x;   // 64 threads
    int base = 0;
    for (int i0 = 0; i0 < NBLK_P; i0 += 64) {
        int i = i0 + lane;
        int v = (i < NBLK_P) ? bcnt[bu * NBLK_P + i] : 0;
        int orig = v;
#pragma unroll
        for (int off = 1; off < 64; off <<= 1) {
            int t = __shfl_up(v, off);
            if (lane >= off) v += t;
        }
        if (i < NBLK_P) bcnt[bu * NBLK_P + i] = base + v - orig;
        base += __shfl(v, 63);
    }
    if (lane == 0) btot[bu] = base;
}

__global__ void bbase_scan_kernel(const int* __restrict__ btot, int* __restrict__ bbase) {
    int acc = 0;
    for (int i = 0; i < NBUCK; ++i) { bbase[i] = acc; acc += btot[i]; }
}

// ---------------- partition edges into bucket-contiguous (src,dst) records ----------------

__global__ void part_scatter_kernel(const int* __restrict__ src, const int* __restrict__ dst,
                                    const int* __restrict__ bcnt, const int* __restrict__ bbase,
                                    int2* __restrict__ part) {
    __shared__ int lh[NBUCK];
    int tid = threadIdx.x;
    for (int i = tid; i < NBUCK; i += 256) lh[i] = 0;
    __syncthreads();
    long base = (long)blockIdx.x * CHUNK;
#pragma unroll
    for (int p = 0; p < CHUNK; p += 256) {
        long e = base + p + tid;
        if (e < N_EDGES) {
            int s = src[e], d = dst[e];
            int bu = d >> BSHIFT;
            int lr = atomicAdd(&lh[bu], 1);
            int pos = bbase[bu] + bcnt[bu * NBLK_P + blockIdx.x] + lr;
            int2 rec; rec.x = s; rec.y = d;
            part[pos] = rec;
        }
    }
}

// ---------------- final scatter, LDS-staged per bucket: coalesced sedge writes ----------------
// one block per bucket; bbase[b] == rowp[b*256] (partition order == CSR order)

__global__ __launch_bounds__(256) void final_scatter_lds_kernel(
        const int2* __restrict__ part, const float* __restrict__ dinv,
        const int* __restrict__ rowp, const int* __restrict__ bbase,
        const int* __restrict__ btot, int2* __restrict__ sedge) {
    __shared__ int lcurs[256];
    __shared__ int2 buf[BCAP];
    int b = blockIdx.x;
    int node0 = b << BSHIFT;
    int start = bbase[b];
    int cnt = btot[b];
    int tid = threadIdx.x;
    {
        int n = node0 + tid;
        lcurs[tid] = (n < N_NODES) ? (rowp[n] - start) : cnt;
    }
    __syncthreads();
    for (int e = tid; e < cnt; e += 256) {
        int2 r = part[start + e];
        int li = r.y - node0;
        int lpos = atomicAdd(&lcurs[li], 1);
        int2 rec; rec.x = r.x; rec.y = __float_as_int(dinv[r.x]);
        if (lpos < BCAP) buf[lpos] = rec;
        else sedge[start + lpos] = rec;   // statistical-impossibility fallback
    }
    __syncthreads();
    int lim = min(cnt, BCAP);
    for (int e = tid; e < lim; e += 256)
        sedge[start + e] = buf[e];
}

// ---------------- conversions ----------------

__global__ void cvt_x_kernel(const float* __restrict__ x, unsigned short* __restrict__ xb) {
    long i = (long)blockIdx.x * blockDim.x + threadIdx.x;   // over n/4
    if (i >= (long)N_NODES * 128 / 4) return;
    float4 v = ((const float4*)x)[i];
    ushort4 o;
    o.x = f2bf(v.x); o.y = f2bf(v.y); o.z = f2bf(v.z); o.w = f2bf(v.w);
    ((ushort4*)xb)[i] = o;
}

// all three weights, transposed+converted: Wt[m][k] = bf16(W[k][m])
__global__ void cvt_w_all_kernel(const float* __restrict__ W1, const float* __restrict__ W2,
                                 const float* __restrict__ W3,
                                 unsigned short* __restrict__ Wt1,
                                 unsigned short* __restrict__ Wt2,
                                 unsigned short* __restrict__ Wt3) {
    int i = blockIdx.x * blockDim.x + threadIdx.x;
    if (i < 32768) {                       // W1: [128][256]
        int k = i >> 8, m = i & 255;
        Wt1[m * 128 + k] = f2bf(W1[i]);
    } else if (i < 65536) {                // W2: [256][128]
        int j = i - 32768;
        int k = j >> 7, m = j & 127;
        Wt2[m * 256 + k] = f2bf(W2[j]);
    } else if (i < 73728) {                // W3: [128][64]
        int j = i - 65536;
        int k = j >> 6, m = j & 63;
        Wt3[m * 128 + k] = f2bf(W3[j]);
    }
}

// ---------------- CSR gather aggregation (bf16 in, bf16/f32 out) ----------------
// one 64-lane wave per dst node; lane owns C/64 channels; 8 gathers in flight
template<int C, bool BIAS, bool RELU, bool LOGSM, bool OUTF32>
__global__ void agg_csr_kernel(const unsigned short* __restrict__ h,
                               const float* __restrict__ dinv,
                               const int* __restrict__ rowptr, const int* __restrict__ deg,
                               const int2* __restrict__ sedge,
                               const float* __restrict__ bias, void* __restrict__ outv) {
    constexpr int V = C / 64;  // 2 for C=128, 1 for C=64
    int gw = (int)((blockIdx.x * (long)blockDim.x + threadIdx.x) >> 6);
    int lane = threadIdx.x & 63;
    if (gw >= N_NODES) return;

    float di = dinv[gw];
    int st = rowptr[gw];
    int cnt = deg[gw];
    float a0, a1 = 0.0f;
    if constexpr (V == 2) {
        unsigned int u = ((const unsigned int*)(h + (long)gw * C))[lane];
        a0 = di * bflo2f(u); a1 = di * bfhi2f(u);
    } else {
        a0 = di * bflo2f(h[(long)gw * C + lane]);
    }

    int k = 0;
    // 8-deep gather block
    for (; k + 8 <= cnt; k += 8) {
        int2 r[8];
#pragma unroll
        for (int j = 0; j < 8; ++j) r[j] = sedge[st + k + j];
        if constexpr (V == 2) {
            unsigned int u[8];
#pragma unroll
            for (int j = 0; j < 8; ++j)
                u[j] = ((const unsigned int*)(h + (long)r[j].x * C))[lane];
#pragma unroll
            for (int j = 0; j < 8; ++j) {
                float w = __int_as_float(r[j].y);
                a0 += w * bflo2f(u[j]); a1 += w * bfhi2f(u[j]);
            }
        } else {
            unsigned short u[8];
#pragma unroll
            for (int j = 0; j < 8; ++j)
                u[j] = h[(long)r[j].x * C + lane];
#pragma unroll
            for (int j = 0; j < 8; ++j)
                a0 += __int_as_float(r[j].y) * bflo2f(u[j]);
        }
    }
    // 4-deep
    for (; k + 4 <= cnt; k += 4) {
        int2 r[4];
#pragma unroll
        for (int j = 0; j < 4; ++j) r[j] = sedge[st + k + j];
        if constexpr (V == 2) {
            unsigned int u[4];
#pragma unroll
            for (int j = 0; j < 4; ++j)
                u[j] = ((const unsigned int*)(h + (long)r[j].x * C))[lane];
#pragma unroll
            for (int j = 0; j < 4; ++j) {
                float w = __int_as_float(r[j].y);
                a0 += w * bflo2f(u[j]); a1 += w * bfhi2f(u[j]);
            }
        } else {
            unsigned short u[4];
#pragma unroll
            for (int j = 0; j < 4; ++j)
                u[j] = h[(long)r[j].x * C + lane];
#pragma unroll
            for (int j = 0; j < 4; ++j)
                a0 += __int_as_float(r[j].y) * bflo2f(u[j]);
        }
    }
    // tail
    for (; k < cnt; ++k) {
        int2 r = sedge[st + k];
        float w = __int_as_float(r.y);
        if constexpr (V == 2) {
            unsigned int u = ((const unsigned int*)(h + (long)r.x * C))[lane];
            a0 += w * bflo2f(u); a1 += w * bfhi2f(u);
        } else {
            a0 += w * bflo2f(h[(long)r.x * C + lane]);
        }
    }

    a0 *= di; a1 *= di;
    if constexpr (BIAS) {
        if constexpr (V == 2) { a0 += bias[lane * 2]; a1 += bias[lane * 2 + 1]; }
        else a0 += bias[lane];
    }
    if constexpr (RELU) { a0 = fmaxf(a0, 0.0f); a1 = fmaxf(a1, 0.0f); }
    if constexpr (LOGSM) {  // V==1 only
        float m = a0;
#pragma unroll
        for (int o = 32; o > 0; o >>= 1) m = fmaxf(m, __shfl_xor(m, o));
        float e = expf(a0 - m), s = e;
#pragma unroll
        for (int o = 32; o > 0; o >>= 1) s += __shfl_xor(s, o);
        a0 = a0 - m - logf(s);
    }
    if constexpr (OUTF32) {
        float* out = (float*)outv;
        if constexpr (V == 2) {
            float2 r; r.x = a0; r.y = a1;
            *(float2*)(out + (long)gw * C + lane * 2) = r;
        } else {
            out[(long)gw * C + lane] = a0;
        }
    } else {
        unsigned short* out = (unsigned short*)outv;
        if constexpr (V == 2) {
            unsigned int up = (unsigned int)f2bf(a0) | ((unsigned int)f2bf(a1) << 16);
            ((unsigned int*)(out + (long)gw * C))[lane] = up;
        } else {
            out[(long)gw * C + lane] = f2bf(a0);
        }
    }
}

// ---------------- bf16 MFMA GEMM ----------------
// C[N,M](bf16) = A[N,K](bf16) @ Wt[M,K]^T (+bias)(relu)
// 64x64 block tile, 4 waves 2x2, each wave 32x32 via mfma_f32_16x16x32_bf16.
template<int K, int M, bool BIAS, bool RELU>
__global__ __launch_bounds__(256) void gemm_mfma_kernel(
        const unsigned short* __restrict__ A,   // [NPAD][K]
        const unsigned short* __restrict__ Bt,  // [M][K]
        const float* __restrict__ bias,         // [M]
        unsigned short* __restrict__ Cb,        // [NPAD][M]
        int N) {
    constexpr int KC = K / 8;                    // 16B chunks per row
    __shared__ unsigned short As[64 * K];
    __shared__ unsigned short Bs[64 * K];

    int tid = threadIdx.x;
    int row0 = blockIdx.x * 64;
    int col0 = blockIdx.y * 64;

    const unsigned short* Ap = A + (long)row0 * K;
    const unsigned short* Bp = Bt + (long)col0 * K;

    // stage both panels; LDS byte = (c*16) ^ ((row&7)<<4)
    for (int c = tid; c < 64 * KC; c += 256) {
        int r = c / KC;
        unsigned int swz = ((unsigned int)c * 16u) ^ ((unsigned int)(r & 7) << 4);
        bf16x8 va = *(const bf16x8*)(Ap + c * 8);
        bf16x8 vb = *(const bf16x8*)(Bp + c * 8);
        *(bf16x8*)((char*)As + swz) = va;
        *(bf16x8*)((char*)Bs + swz) = vb;
    }
    __syncthreads();

    int lane = tid & 63;
    int wv = tid >> 6;
    int wr = wv >> 1, wc = wv & 1;      // wave tile origin (wr*32, wc*32)
    int lr = lane & 15;
    int kg = lane >> 4;                 // k-group: k = kg*8 + j

    f32x4 acc[2][2] = {};

    for (int k0 = 0; k0 < K; k0 += 32) {
        bf16x8 a[2], b[2];
#pragma unroll
        for (int mi = 0; mi < 2; ++mi) {
            int r = wr * 32 + mi * 16 + lr;
            unsigned int byteo = (unsigned int)((r * K + k0 + kg * 8) * 2);
            byteo ^= (unsigned int)((r & 7) << 4);
            a[mi] = *(const bf16x8*)((const char*)As + byteo);
        }
#pragma unroll
        for (int ni = 0; ni < 2; ++ni) {
            int r = wc * 32 + ni * 16 + lr;
            unsigned int byteo = (unsigned int)((r * K + k0 + kg * 8) * 2);
            byteo ^= (unsigned int)((r & 7) << 4);
            b[ni] = *(const bf16x8*)((const char*)Bs + byteo);
        }
#pragma unroll
        for (int mi = 0; mi < 2; ++mi)
#pragma unroll
            for (int ni = 0; ni < 2; ++ni)
                acc[mi][ni] = __builtin_amdgcn_mfma_f32_16x16x32_bf16(
                    a[mi], b[ni], acc[mi][ni], 0, 0, 0);
    }

    // epilogue: C/D layout col=lane&15, row=(lane>>4)*4+i
#pragma unroll
    for (int mi = 0; mi < 2; ++mi) {
#pragma unroll
        for (int ni = 0; ni < 2; ++ni) {
            int col = col0 + wc * 32 + ni * 16 + lr;
            float bv = BIAS ? bias[col] : 0.0f;
#pragma unroll
            for (int i = 0; i < 4; ++i) {
                int row = row0 + wr * 32 + mi * 16 + kg * 4 + i;
                if (row < N) {
                    float v = acc[mi][ni][i] + bv;
                    if (RELU) v = fmaxf(v, 0.0f);
                    Cb[(long)row * M + col] = f2bf(v);
                }
            }
        }
    }
}

// ---------------- launch ----------------

extern "C" void kernel_launch(void* const* d_in, const int* in_sizes, int n_in,
                              void* d_out, int out_size, void* d_ws, size_t ws_size,
                              hipStream_t stream) {
    const float* x  = (const float*)d_in[0];
    const int* edge = (const int*)d_in[1];
    const float* W1 = (const float*)d_in[2];
    const float* b1 = (const float*)d_in[3];
    const float* W2 = (const float*)d_in[4];
    const float* b2 = (const float*)d_in[5];
    const float* W3 = (const float*)d_in[6];
    const float* b3 = (const float*)d_in[7];
    float* out = (float*)d_out;

    const int* src = edge;
    const int* dst = edge + N_EDGES;

    // workspace layout (float-element offsets)
    float* ws    = (float*)d_ws;
    float* dinv  = ws;                                   // N
    int*   degi  = (int*)(ws + 100000);                  // N
    int*   rowp  = (int*)(ws + 200000);                  // N
    int*   bsum  = (int*)(ws + 300000);                  // 391 (alloc 512)
    int*   btot  = (int*)(ws + 300512);                  // 391 (alloc 512)
    int*   bbase = (int*)(ws + 301024);                  // 391 (alloc 512)
    int*   bcnt  = (int*)(ws + 301536);                  // NBUCK*NBLK_P = 152881 (alloc 153600)
    int2*  sedge = (int2*)(ws + 455136);                 // E*2 ints (8B aligned)
    unsigned short* P1  = (unsigned short*)(ws + 3655136);   // [NPAD][128]
    unsigned short* P2  = P1 + (size_t)NPAD * 128;           // [NPAD][128]
    unsigned short* P3  = P2 + (size_t)NPAD * 128;           // [NPAD][256]
    unsigned short* Wt1 = P3 + (size_t)NPAD * 256;           // [256][128]
    unsigned short* Wt2 = Wt1 + 128 * 256;                   // [128][256]
    unsigned short* Wt3 = Wt2 + 256 * 128;                   // [64][128]
    int2*  part  = (int2*)P3;   // scratch reuse: consumed before gemm1 writes P3

    const int BT = 256;
    int gAgg = (int)(((long)N_NODES * 64 + BT - 1) / BT);
    int gRows = (N_NODES + 63) / 64;   // 1563

    // --- fused degree + bucket counts (reads dst once) ---
    hipMemsetAsync(degi, 0, N_NODES * sizeof(int), stream);
    edge_count_kernel<<<NBLK_P, BT, 0, stream>>>(dst, degi, bcnt);

    // --- node scan (+dinv) ---
    scan1_kernel<<<NBLK_SCAN, 256, 0, stream>>>(degi, rowp, bsum, dinv);
    scan2_kernel<<<1, 512, 0, stream>>>(bsum);
    scan3_kernel<<<NBLK_SCAN, 256, 0, stream>>>(rowp, bsum);

    // --- bucket scan + partition + LDS-staged final scatter ---
    bucket_scan_kernel<<<NBUCK, 64, 0, stream>>>(bcnt, btot);
    bbase_scan_kernel<<<1, 1, 0, stream>>>(btot, bbase);
    part_scatter_kernel<<<NBLK_P, BT, 0, stream>>>(src, dst, bcnt, bbase, part);
    final_scatter_lds_kernel<<<NBUCK, BT, 0, stream>>>(part, dinv, rowp, bbase, btot, sedge);

    // --- conversions ---
    cvt_x_kernel<<<(int)(((long)N_NODES * 128 / 4 + BT - 1) / BT), BT, 0, stream>>>(x, P1);
    cvt_w_all_kernel<<<(73728 + BT - 1) / BT, BT, 0, stream>>>(W1, W2, W3, Wt1, Wt2, Wt3);

    // --- layer 1: agg(x) [P1->P2], gemm 128->256 +b1 +relu [P2->P3] ---
    agg_csr_kernel<128, false, false, false, false><<<gAgg, BT, 0, stream>>>(
        P1, dinv, rowp, degi, sedge, nullptr, P2);
    {
        dim3 g(gRows, 4);
        gemm_mfma_kernel<128, 256, true, true><<<g, BT, 0, stream>>>(P2, Wt1, b1, P3, N_NODES);
    }

    // --- layer 2: gemm 256->128 [P3->P1], agg +b2 +relu [P1->P2] ---
    {
        dim3 g(gRows, 2);
        gemm_mfma_kernel<256, 128, false, false><<<g, BT, 0, stream>>>(P3, Wt2, nullptr, P1, N_NODES);
    }
    agg_csr_kernel<128, true, true, false, false><<<gAgg, BT, 0, stream>>>(
        P1, dinv, rowp, degi, sedge, b2, P2);

    // --- layer 3: gemm 128->64 [P2->P1], agg +b3 +relu +logsm [P1->out] ---
    {
        dim3 g(gRows, 1);
        gemm_mfma_kernel<128, 64, false, false><<<g, BT, 0, stream>>>(P2, Wt3, nullptr, P1, N_NODES);
    }
    agg_csr_kernel<64, true, true, true, true><<<gAgg, BT, 0, stream>>>(
        P1, dinv, rowp, degi, sedge, b3, out);

    (void)in_sizes; (void)n_in; (void)out_size; (void)ws_size;
}

// Round 10
// 332.799 us; speedup vs baseline: 3.1099x; 1.2334x over previous
//
#include <hip/hip_runtime.h>
#include <math.h>

#define N_NODES 100000
#define N_EDGES 1600000
#define CHUNK 4096
#define NBLK_P ((N_EDGES + CHUNK - 1) / CHUNK)  // 391
#define NPAD 100064                          // 64-row padded for GEMM staging
#define BSHIFT 8                             // 256 nodes per bucket
#define NBUCK ((N_NODES + 255) / 256)        // 391 buckets
#define BCAP 6144                            // LDS record capacity per bucket

typedef __attribute__((ext_vector_type(8))) short bf16x8;
typedef __attribute__((ext_vector_type(4))) float f32x4;

__device__ __forceinline__ unsigned short f2bf(float f) {
    unsigned int u = __builtin_bit_cast(unsigned int, f);
    u += 0x7fffu + ((u >> 16) & 1u);          // RNE
    return (unsigned short)(u >> 16);
}
__device__ __forceinline__ float bflo2f(unsigned int u) {   // low 16 bits = bf16
    return __builtin_bit_cast(float, u << 16);
}
__device__ __forceinline__ float bfhi2f(unsigned int u) {   // high 16 bits = bf16
    return __builtin_bit_cast(float, u & 0xffff0000u);
}

// ---------------- bucket count only (NO global degree atomics) ----------------

__global__ __launch_bounds__(1024) void edge_count_kernel(const int* __restrict__ dst,
                                                          int* __restrict__ bcnt) {
    __shared__ int lh[NBUCK];
    int tid = threadIdx.x;
    if (tid < NBUCK) lh[tid] = 0;
    __syncthreads();
    long base = (long)blockIdx.x * CHUNK;
#pragma unroll
    for (int p = 0; p < CHUNK; p += 1024) {
        long e = base + p + tid;
        if (e < N_EDGES) atomicAdd(&lh[dst[e] >> BSHIFT], 1);
    }
    __syncthreads();
    if (tid < NBUCK) bcnt[tid * NBLK_P + blockIdx.x] = lh[tid];
}

// ---------------- bucket scan over blocks (one wave per bucket) ----------------

__global__ void bucket_scan_kernel(int* __restrict__ bcnt, int* __restrict__ btot) {
    int bu = blockIdx.x, lane = threadIdx.x;   // 64 threads
    int base = 0;
    for (int i0 = 0; i0 < NBLK_P; i0 += 64) {
        int i = i0 + lane;
        int v = (i < NBLK_P) ? bcnt[bu * NBLK_P + i] : 0;
        int orig = v;
#pragma unroll
        for (int off = 1; off < 64; off <<= 1) {
            int t = __shfl_up(v, off);
            if (lane >= off) v += t;
        }
        if (i < NBLK_P) bcnt[bu * NBLK_P + i] = base + v - orig;
        base += __shfl(v, 63);
    }
    if (lane == 0) btot[bu] = base;
}

// parallel exclusive scan over NBUCK totals (single 512-thread block)
__global__ void bbase_scan_kernel(const int* __restrict__ btot, int* __restrict__ bbase) {
    __shared__ int tmp[512];
    int i = threadIdx.x;
    int v = (i < NBUCK) ? btot[i] : 0;
    tmp[i] = v;
    __syncthreads();
    for (int off = 1; off < 512; off <<= 1) {
        int t = (i >= off) ? tmp[i - off] : 0;
        __syncthreads();
        tmp[i] += t;
        __syncthreads();
    }
    if (i < NBUCK) bbase[i] = tmp[i] - v;
}

// ---------------- partition edges into bucket-contiguous (src,dst) records ----------------

__global__ __launch_bounds__(1024) void part_scatter_kernel(
        const int* __restrict__ src, const int* __restrict__ dst,
        const int* __restrict__ bcnt, const int* __restrict__ bbase,
        int2* __restrict__ part) {
    __shared__ int lh[NBUCK];
    int tid = threadIdx.x;
    if (tid < NBUCK) lh[tid] = 0;
    __syncthreads();
    long base = (long)blockIdx.x * CHUNK;
#pragma unroll
    for (int p = 0; p < CHUNK; p += 1024) {
        long e = base + p + tid;
        if (e < N_EDGES) {
            int s = src[e], d = dst[e];
            int bu = d >> BSHIFT;
            int lr = atomicAdd(&lh[bu], 1);
            int pos = bbase[bu] + bcnt[bu * NBLK_P + blockIdx.x] + lr;
            int2 rec; rec.x = s; rec.y = d;
            part[pos] = rec;
        }
    }
}

// ---------------- per-bucket degrees -> rowp + dinv (LDS count + local scan) ----------------
// rowp[n] = bbase[bucket] + prefix within bucket; no global atomics, no node scan

__global__ __launch_bounds__(512) void bucket_deg_kernel(
        const int2* __restrict__ part, const int* __restrict__ bbase,
        const int* __restrict__ btot, int* __restrict__ rowp,
        float* __restrict__ dinv) {
    __shared__ int lcnt[256];
    __shared__ int lscan[256];
    int b = blockIdx.x;
    int node0 = b << BSHIFT;
    int start = bbase[b];
    int cnt = btot[b];
    int tid = threadIdx.x;
    if (tid < 256) lcnt[tid] = 0;
    __syncthreads();
    for (int e = tid; e < cnt; e += 512)
        atomicAdd(&lcnt[part[start + e].y - node0], 1);
    __syncthreads();
    int v = 0;
    if (tid < 256) { v = lcnt[tid]; lscan[tid] = v; }
    __syncthreads();
    for (int off = 1; off < 256; off <<= 1) {
        int t = (tid < 256 && tid >= off) ? lscan[tid - off] : 0;
        __syncthreads();
        if (tid < 256) lscan[tid] += t;
        __syncthreads();
    }
    if (tid < 256) {
        int n = node0 + tid;
        if (n < N_NODES) {
            rowp[n] = start + lscan[tid] - v;      // exclusive prefix
            dinv[n] = rsqrtf(1.0f + (float)v);     // +1 self-loop
        }
    }
    if (b == NBUCK - 1 && tid == 0) rowp[N_NODES] = N_EDGES;
}

// ---------------- final scatter, LDS-staged per bucket: coalesced sedge writes ----------------

__global__ __launch_bounds__(512) void final_scatter_lds_kernel(
        const int2* __restrict__ part, const float* __restrict__ dinv,
        const int* __restrict__ rowp, const int* __restrict__ bbase,
        const int* __restrict__ btot, int2* __restrict__ sedge) {
    __shared__ int lcurs[256];
    __shared__ int2 buf[BCAP];
    int b = blockIdx.x;
    int node0 = b << BSHIFT;
    int start = bbase[b];
    int cnt = btot[b];
    int tid = threadIdx.x;
    if (tid < 256) {
        int n = node0 + tid;
        lcurs[tid] = (n < N_NODES) ? (rowp[n] - start) : cnt;
    }
    __syncthreads();
    for (int e = tid; e < cnt; e += 512) {
        int2 r = part[start + e];
        int lpos = atomicAdd(&lcurs[r.y - node0], 1);
        int2 rec; rec.x = r.x; rec.y = __float_as_int(dinv[r.x]);
        if (lpos < BCAP) buf[lpos] = rec;
        else sedge[start + lpos] = rec;   // statistical-impossibility fallback
    }
    __syncthreads();
    int lim = min(cnt, BCAP);
    for (int e = tid; e < lim; e += 512)
        sedge[start + e] = buf[e];
}

// ---------------- conversions ----------------

__global__ void cvt_x_kernel(const float* __restrict__ x, unsigned short* __restrict__ xb) {
    long i = (long)blockIdx.x * blockDim.x + threadIdx.x;   // over n/4
    if (i >= (long)N_NODES * 128 / 4) return;
    float4 v = ((const float4*)x)[i];
    ushort4 o;
    o.x = f2bf(v.x); o.y = f2bf(v.y); o.z = f2bf(v.z); o.w = f2bf(v.w);
    ((ushort4*)xb)[i] = o;
}

// all three weights, transposed+converted: Wt[m][k] = bf16(W[k][m])
__global__ void cvt_w_all_kernel(const float* __restrict__ W1, const float* __restrict__ W2,
                                 const float* __restrict__ W3,
                                 unsigned short* __restrict__ Wt1,
                                 unsigned short* __restrict__ Wt2,
                                 unsigned short* __restrict__ Wt3) {
    int i = blockIdx.x * blockDim.x + threadIdx.x;
    if (i < 32768) {                       // W1: [128][256]
        int k = i >> 8, m = i & 255;
        Wt1[m * 128 + k] = f2bf(W1[i]);
    } else if (i < 65536) {                // W2: [256][128]
        int j = i - 32768;
        int k = j >> 7, m = j & 127;
        Wt2[m * 256 + k] = f2bf(W2[j]);
    } else if (i < 73728) {                // W3: [128][64]
        int j = i - 65536;
        int k = j >> 6, m = j & 63;
        Wt3[m * 128 + k] = f2bf(W3[j]);
    }
}

// ---------------- CSR gather aggregation (bf16 in, bf16/f32 out) ----------------
// one 64-lane wave per dst node; cnt = rowp[n+1]-rowp[n]; 8 gathers in flight
template<int C, bool BIAS, bool RELU, bool LOGSM, bool OUTF32>
__global__ void agg_csr_kernel(const unsigned short* __restrict__ h,
                               const float* __restrict__ dinv,
                               const int* __restrict__ rowptr,
                               const int2* __restrict__ sedge,
                               const float* __restrict__ bias, void* __restrict__ outv) {
    constexpr int V = C / 64;  // 2 for C=128, 1 for C=64
    int gw = (int)((blockIdx.x * (long)blockDim.x + threadIdx.x) >> 6);
    int lane = threadIdx.x & 63;
    if (gw >= N_NODES) return;

    float di = dinv[gw];
    int st = rowptr[gw];
    int cnt = rowptr[gw + 1] - st;
    float a0, a1 = 0.0f;
    if constexpr (V == 2) {
        unsigned int u = ((const unsigned int*)(h + (long)gw * C))[lane];
        a0 = di * bflo2f(u); a1 = di * bfhi2f(u);
    } else {
        a0 = di * bflo2f(h[(long)gw * C + lane]);
    }

    int k = 0;
    for (; k + 8 <= cnt; k += 8) {
        int2 r[8];
#pragma unroll
        for (int j = 0; j < 8; ++j) r[j] = sedge[st + k + j];
        if constexpr (V == 2) {
            unsigned int u[8];
#pragma unroll
            for (int j = 0; j < 8; ++j)
                u[j] = ((const unsigned int*)(h + (long)r[j].x * C))[lane];
#pragma unroll
            for (int j = 0; j < 8; ++j) {
                float w = __int_as_float(r[j].y);
                a0 += w * bflo2f(u[j]); a1 += w * bfhi2f(u[j]);
            }
        } else {
            unsigned short u[8];
#pragma unroll
            for (int j = 0; j < 8; ++j)
                u[j] = h[(long)r[j].x * C + lane];
#pragma unroll
            for (int j = 0; j < 8; ++j)
                a0 += __int_as_float(r[j].y) * bflo2f(u[j]);
        }
    }
    for (; k + 4 <= cnt; k += 4) {
        int2 r[4];
#pragma unroll
        for (int j = 0; j < 4; ++j) r[j] = sedge[st + k + j];
        if constexpr (V == 2) {
            unsigned int u[4];
#pragma unroll
            for (int j = 0; j < 4; ++j)
                u[j] = ((const unsigned int*)(h + (long)r[j].x * C))[lane];
#pragma unroll
            for (int j = 0; j < 4; ++j) {
                float w = __int_as_float(r[j].y);
                a0 += w * bflo2f(u[j]); a1 += w * bfhi2f(u[j]);
            }
        } else {
            unsigned short u[4];
#pragma unroll
            for (int j = 0; j < 4; ++j)
                u[j] = h[(long)r[j].x * C + lane];
#pragma unroll
            for (int j = 0; j < 4; ++j)
                a0 += __int_as_float(r[j].y) * bflo2f(u[j]);
        }
    }
    for (; k < cnt; ++k) {
        int2 r = sedge[st + k];
        float w = __int_as_float(r.y);
        if constexpr (V == 2) {
            unsigned int u = ((const unsigned int*)(h + (long)r.x * C))[lane];
            a0 += w * bflo2f(u); a1 += w * bfhi2f(u);
        } else {
            a0 += w * bflo2f(h[(long)r.x * C + lane]);
        }
    }

    a0 *= di; a1 *= di;
    if constexpr (BIAS) {
        if constexpr (V == 2) { a0 += bias[lane * 2]; a1 += bias[lane * 2 + 1]; }
        else a0 += bias[lane];
    }
    if constexpr (RELU) { a0 = fmaxf(a0, 0.0f); a1 = fmaxf(a1, 0.0f); }
    if constexpr (LOGSM) {  // V==1 only
        float m = a0;
#pragma unroll
        for (int o = 32; o > 0; o >>= 1) m = fmaxf(m, __shfl_xor(m, o));
        float e = expf(a0 - m), s = e;
#pragma unroll
        for (int o = 32; o > 0; o >>= 1) s += __shfl_xor(s, o);
        a0 = a0 - m - logf(s);
    }
    if constexpr (OUTF32) {
        float* out = (float*)outv;
        if constexpr (V == 2) {
            float2 r; r.x = a0; r.y = a1;
            *(float2*)(out + (long)gw * C + lane * 2) = r;
        } else {
            out[(long)gw * C + lane] = a0;
        }
    } else {
        unsigned short* out = (unsigned short*)outv;
        if constexpr (V == 2) {
            unsigned int up = (unsigned int)f2bf(a0) | ((unsigned int)f2bf(a1) << 16);
            ((unsigned int*)(out + (long)gw * C))[lane] = up;
        } else {
            out[(long)gw * C + lane] = f2bf(a0);
        }
    }
}

// ---------------- bf16 MFMA GEMM ----------------
// C[N,M](bf16) = A[N,K](bf16) @ Wt[M,K]^T (+bias)(relu)
// 64x64 block tile, 4 waves 2x2, each wave 32x32 via mfma_f32_16x16x32_bf16.
template<int K, int M, bool BIAS, bool RELU>
__global__ __launch_bounds__(256) void gemm_mfma_kernel(
        const unsigned short* __restrict__ A,   // [NPAD][K]
        const unsigned short* __restrict__ Bt,  // [M][K]
        const float* __restrict__ bias,         // [M]
        unsigned short* __restrict__ Cb,        // [NPAD][M]
        int N) {
    constexpr int KC = K / 8;                    // 16B chunks per row
    __shared__ unsigned short As[64 * K];
    __shared__ unsigned short Bs[64 * K];

    int tid = threadIdx.x;
    int row0 = blockIdx.x * 64;
    int col0 = blockIdx.y * 64;

    const unsigned short* Ap = A + (long)row0 * K;
    const unsigned short* Bp = Bt + (long)col0 * K;

    // stage both panels; LDS byte = (c*16) ^ ((row&7)<<4)
    for (int c = tid; c < 64 * KC; c += 256) {
        int r = c / KC;
        unsigned int swz = ((unsigned int)c * 16u) ^ ((unsigned int)(r & 7) << 4);
        bf16x8 va = *(const bf16x8*)(Ap + c * 8);
        bf16x8 vb = *(const bf16x8*)(Bp + c * 8);
        *(bf16x8*)((char*)As + swz) = va;
        *(bf16x8*)((char*)Bs + swz) = vb;
    }
    __syncthreads();

    int lane = tid & 63;
    int wv = tid >> 6;
    int wr = wv >> 1, wc = wv & 1;      // wave tile origin (wr*32, wc*32)
    int lr = lane & 15;
    int kg = lane >> 4;                 // k-group: k = kg*8 + j

    f32x4 acc[2][2] = {};

    for (int k0 = 0; k0 < K; k0 += 32) {
        bf16x8 a[2], b[2];
#pragma unroll
        for (int mi = 0; mi < 2; ++mi) {
            int r = wr * 32 + mi * 16 + lr;
            unsigned int byteo = (unsigned int)((r * K + k0 + kg * 8) * 2);
            byteo ^= (unsigned int)((r & 7) << 4);
            a[mi] = *(const bf16x8*)((const char*)As + byteo);
        }
#pragma unroll
        for (int ni = 0; ni < 2; ++ni) {
            int r = wc * 32 + ni * 16 + lr;
            unsigned int byteo = (unsigned int)((r * K + k0 + kg * 8) * 2);
            byteo ^= (unsigned int)((r & 7) << 4);
            b[ni] = *(const bf16x8*)((const char*)Bs + byteo);
        }
#pragma unroll
        for (int mi = 0; mi < 2; ++mi)
#pragma unroll
            for (int ni = 0; ni < 2; ++ni)
                acc[mi][ni] = __builtin_amdgcn_mfma_f32_16x16x32_bf16(
                    a[mi], b[ni], acc[mi][ni], 0, 0, 0);
    }

    // epilogue: C/D layout col=lane&15, row=(lane>>4)*4+i
#pragma unroll
    for (int mi = 0; mi < 2; ++mi) {
#pragma unroll
        for (int ni = 0; ni < 2; ++ni) {
            int col = col0 + wc * 32 + ni * 16 + lr;
            float bv = BIAS ? bias[col] : 0.0f;
#pragma unroll
            for (int i = 0; i < 4; ++i) {
                int row = row0 + wr * 32 + mi * 16 + kg * 4 + i;
                if (row < N) {
                    float v = acc[mi][ni][i] + bv;
                    if (RELU) v = fmaxf(v, 0.0f);
                    Cb[(long)row * M + col] = f2bf(v);
                }
            }
        }
    }
}

// ---------------- launch ----------------

extern "C" void kernel_launch(void* const* d_in, const int* in_sizes, int n_in,
                              void* d_out, int out_size, void* d_ws, size_t ws_size,
                              hipStream_t stream) {
    const float* x  = (const float*)d_in[0];
    const int* edge = (const int*)d_in[1];
    const float* W1 = (const float*)d_in[2];
    const float* b1 = (const float*)d_in[3];
    const float* W2 = (const float*)d_in[4];
    const float* b2 = (const float*)d_in[5];
    const float* W3 = (const float*)d_in[6];
    const float* b3 = (const float*)d_in[7];
    float* out = (float*)d_out;

    const int* src = edge;
    const int* dst = edge + N_EDGES;

    // workspace layout (float-element offsets)
    float* ws    = (float*)d_ws;
    float* dinv  = ws;                                   // N
    int*   rowp  = (int*)(ws + 100000);                  // N+1 (alloc 100352)
    int*   btot  = (int*)(ws + 200352);                  // 391 (alloc 512)
    int*   bbase = (int*)(ws + 200864);                  // 391 (alloc 512)
    int*   bcnt  = (int*)(ws + 201376);                  // 391*391=152881 (alloc 153600)
    int2*  sedge = (int2*)(ws + 354976);                 // E*2 ints (8B aligned)
    unsigned short* P1  = (unsigned short*)(ws + 3554976);   // [NPAD][128]
    unsigned short* P2  = P1 + (size_t)NPAD * 128;           // [NPAD][128]
    unsigned short* P3  = P2 + (size_t)NPAD * 128;           // [NPAD][256]
    unsigned short* Wt1 = P3 + (size_t)NPAD * 256;           // [256][128]
    unsigned short* Wt2 = Wt1 + 128 * 256;                   // [128][256]
    unsigned short* Wt3 = Wt2 + 256 * 128;                   // [64][128]
    int2*  part  = (int2*)P3;   // scratch reuse: consumed before gemm1 writes P3

    const int BT = 256;
    int gAgg = (int)(((long)N_NODES * 64 + BT - 1) / BT);
    int gRows = (N_NODES + 63) / 64;   // 1563

    // --- bucket counts (reads dst once; LDS-only atomics) ---
    edge_count_kernel<<<NBLK_P, 1024, 0, stream>>>(dst, bcnt);

    // --- bucket scans + partition ---
    bucket_scan_kernel<<<NBUCK, 64, 0, stream>>>(bcnt, btot);
    bbase_scan_kernel<<<1, 512, 0, stream>>>(btot, bbase);
    part_scatter_kernel<<<NBLK_P, 1024, 0, stream>>>(src, dst, bcnt, bbase, part);

    // --- per-bucket degrees -> rowp + dinv; then coalesced CSR scatter ---
    bucket_deg_kernel<<<NBUCK, 512, 0, stream>>>(part, bbase, btot, rowp, dinv);
    final_scatter_lds_kernel<<<NBUCK, 512, 0, stream>>>(part, dinv, rowp, bbase, btot, sedge);

    // --- conversions ---
    cvt_x_kernel<<<(int)(((long)N_NODES * 128 / 4 + BT - 1) / BT), BT, 0, stream>>>(x, P1);
    cvt_w_all_kernel<<<(73728 + BT - 1) / BT, BT, 0, stream>>>(W1, W2, W3, Wt1, Wt2, Wt3);

    // --- layer 1: agg(x) [P1->P2], gemm 128->256 +b1 +relu [P2->P3] ---
    agg_csr_kernel<128, false, false, false, false><<<gAgg, BT, 0, stream>>>(
        P1, dinv, rowp, sedge, nullptr, P2);
    {
        dim3 g(gRows, 4);
        gemm_mfma_kernel<128, 256, true, true><<<g, BT, 0, stream>>>(P2, Wt1, b1, P3, N_NODES);
    }

    // --- layer 2: gemm 256->128 [P3->P1], agg +b2 +relu [P1->P2] ---
    {
        dim3 g(gRows, 2);
        gemm_mfma_kernel<256, 128, false, false><<<g, BT, 0, stream>>>(P3, Wt2, nullptr, P1, N_NODES);
    }
    agg_csr_kernel<128, true, true, false, false><<<gAgg, BT, 0, stream>>>(
        P1, dinv, rowp, sedge, b2, P2);

    // --- layer 3: gemm 128->64 [P2->P1], agg +b3 +relu +logsm [P1->out] ---
    {
        dim3 g(gRows, 1);
        gemm_mfma_kernel<128, 64, false, false><<<g, BT, 0, stream>>>(P2, Wt3, nullptr, P1, N_NODES);
    }
    agg_csr_kernel<64, true, true, true, true><<<gAgg, BT, 0, stream>>>(
        P1, dinv, rowp, sedge, b3, out);

    (void)in_sizes; (void)n_in; (void)out_size; (void)ws_size;
}

// Round 11
// 332.508 us; speedup vs baseline: 3.1126x; 1.0009x over previous
//
#include <hip/hip_runtime.h>
#include <math.h>

#define N_NODES 100000
#define N_EDGES 1600000
#define CHUNK 4096
#define NBLK_P ((N_EDGES + CHUNK - 1) / CHUNK)  // 391
#define NPAD 100064                          // 64-row padded for GEMM staging
#define BSHIFT 8                             // 256 nodes per bucket
#define NBUCK ((N_NODES + 255) / 256)        // 391 buckets
#define BCAP 6144                            // LDS record capacity per bucket

typedef __attribute__((ext_vector_type(8))) short bf16x8;
typedef __attribute__((ext_vector_type(4))) float f32x4;

__device__ __forceinline__ unsigned short f2bf(float f) {
    unsigned int u = __builtin_bit_cast(unsigned int, f);
    u += 0x7fffu + ((u >> 16) & 1u);          // RNE
    return (unsigned short)(u >> 16);
}
__device__ __forceinline__ float bflo2f(unsigned int u) {   // low 16 bits = bf16
    return __builtin_bit_cast(float, u << 16);
}
__device__ __forceinline__ float bfhi2f(unsigned int u) {   // high 16 bits = bf16
    return __builtin_bit_cast(float, u & 0xffff0000u);
}

// ---------------- bucket count only (LDS atomics) ----------------

__global__ __launch_bounds__(1024) void edge_count_kernel(const int* __restrict__ dst,
                                                          int* __restrict__ bcnt) {
    __shared__ int lh[NBUCK];
    int tid = threadIdx.x;
    if (tid < NBUCK) lh[tid] = 0;
    __syncthreads();
    long base = (long)blockIdx.x * CHUNK;
#pragma unroll
    for (int p = 0; p < CHUNK; p += 1024) {
        long e = base + p + tid;
        if (e < N_EDGES) atomicAdd(&lh[dst[e] >> BSHIFT], 1);
    }
    __syncthreads();
    if (tid < NBUCK) bcnt[tid * NBLK_P + blockIdx.x] = lh[tid];
}

// ---------------- bucket scan over blocks (one wave per bucket) ----------------

__global__ void bucket_scan_kernel(int* __restrict__ bcnt, int* __restrict__ btot) {
    int bu = blockIdx.x, lane = threadIdx.x;   // 64 threads
    int base = 0;
    for (int i0 = 0; i0 < NBLK_P; i0 += 64) {
        int i = i0 + lane;
        int v = (i < NBLK_P) ? bcnt[bu * NBLK_P + i] : 0;
        int orig = v;
#pragma unroll
        for (int off = 1; off < 64; off <<= 1) {
            int t = __shfl_up(v, off);
            if (lane >= off) v += t;
        }
        if (i < NBLK_P) bcnt[bu * NBLK_P + i] = base + v - orig;
        base += __shfl(v, 63);
    }
    if (lane == 0) btot[bu] = base;
}

// parallel exclusive scan over NBUCK totals (single 512-thread block)
__global__ void bbase_scan_kernel(const int* __restrict__ btot, int* __restrict__ bbase) {
    __shared__ int tmp[512];
    int i = threadIdx.x;
    int v = (i < NBUCK) ? btot[i] : 0;
    tmp[i] = v;
    __syncthreads();
    for (int off = 1; off < 512; off <<= 1) {
        int t = (i >= off) ? tmp[i - off] : 0;
        __syncthreads();
        tmp[i] += t;
        __syncthreads();
    }
    if (i < NBUCK) bbase[i] = tmp[i] - v;
}

// ---------------- partition edges; record packed: src | (d&255)<<17 ----------------

__global__ __launch_bounds__(1024) void part_scatter_kernel(
        const int* __restrict__ src, const int* __restrict__ dst,
        const int* __restrict__ bcnt, const int* __restrict__ bbase,
        int* __restrict__ part) {
    __shared__ int lh[NBUCK];
    int tid = threadIdx.x;
    if (tid < NBUCK) lh[tid] = 0;
    __syncthreads();
    long base = (long)blockIdx.x * CHUNK;
#pragma unroll
    for (int p = 0; p < CHUNK; p += 1024) {
        long e = base + p + tid;
        if (e < N_EDGES) {
            int s = src[e], d = dst[e];
            int bu = d >> BSHIFT;
            int lr = atomicAdd(&lh[bu], 1);
            int pos = bbase[bu] + bcnt[bu * NBLK_P + blockIdx.x] + lr;
            part[pos] = s | ((d & 255) << 17);
        }
    }
}

// ---------------- per-bucket degrees -> rowp + dinv (LDS count + local scan) ----------------

__global__ __launch_bounds__(512) void bucket_deg_kernel(
        const int* __restrict__ part, const int* __restrict__ bbase,
        const int* __restrict__ btot, int* __restrict__ rowp,
        float* __restrict__ dinv) {
    __shared__ int lcnt[256];
    __shared__ int lscan[256];
    int b = blockIdx.x;
    int node0 = b << BSHIFT;
    int start = bbase[b];
    int cnt = btot[b];
    int tid = threadIdx.x;
    if (tid < 256) lcnt[tid] = 0;
    __syncthreads();
    for (int e = tid; e < cnt; e += 512)
        atomicAdd(&lcnt[part[start + e] >> 17], 1);
    __syncthreads();
    int v = 0;
    if (tid < 256) { v = lcnt[tid]; lscan[tid] = v; }
    __syncthreads();
    for (int off = 1; off < 256; off <<= 1) {
        int t = (tid < 256 && tid >= off) ? lscan[tid - off] : 0;
        __syncthreads();
        if (tid < 256) lscan[tid] += t;
        __syncthreads();
    }
    if (tid < 256) {
        int n = node0 + tid;
        if (n < N_NODES) {
            rowp[n] = start + lscan[tid] - v;      // exclusive prefix
            dinv[n] = rsqrtf(1.0f + (float)v);     // +1 self-loop
        }
    }
    if (b == NBUCK - 1 && tid == 0) rowp[N_NODES] = N_EDGES;
}

// ---------------- final scatter, LDS-staged per bucket: coalesced sedge writes ----------------

__global__ __launch_bounds__(512) void final_scatter_lds_kernel(
        const int* __restrict__ part, const float* __restrict__ dinv,
        const int* __restrict__ rowp, const int* __restrict__ bbase,
        const int* __restrict__ btot, int2* __restrict__ sedge) {
    __shared__ int lcurs[256];
    __shared__ int2 buf[BCAP];
    int b = blockIdx.x;
    int node0 = b << BSHIFT;
    int start = bbase[b];
    int cnt = btot[b];
    int tid = threadIdx.x;
    if (tid < 256) {
        int n = node0 + tid;
        lcurs[tid] = (n < N_NODES) ? (rowp[n] - start) : cnt;
    }
    __syncthreads();
    for (int e = tid; e < cnt; e += 512) {
        int r = part[start + e];
        int s = r & 0x1FFFF;
        int lpos = atomicAdd(&lcurs[r >> 17], 1);
        int2 rec; rec.x = s; rec.y = __float_as_int(dinv[s]);
        if (lpos < BCAP) buf[lpos] = rec;
        else sedge[start + lpos] = rec;   // statistical-impossibility fallback
    }
    __syncthreads();
    int lim = min(cnt, BCAP);
    for (int e = tid; e < lim; e += 512)
        sedge[start + e] = buf[e];
}

// ---------------- conversions ----------------

__global__ void cvt_x_kernel(const float* __restrict__ x, unsigned short* __restrict__ xb) {
    long i = (long)blockIdx.x * blockDim.x + threadIdx.x;   // over n/4
    if (i >= (long)N_NODES * 128 / 4) return;
    float4 v = ((const float4*)x)[i];
    ushort4 o;
    o.x = f2bf(v.x); o.y = f2bf(v.y); o.z = f2bf(v.z); o.w = f2bf(v.w);
    ((ushort4*)xb)[i] = o;
}

// all three weights, transposed+converted: Wt[m][k] = bf16(W[k][m])
__global__ void cvt_w_all_kernel(const float* __restrict__ W1, const float* __restrict__ W2,
                                 const float* __restrict__ W3,
                                 unsigned short* __restrict__ Wt1,
                                 unsigned short* __restrict__ Wt2,
                                 unsigned short* __restrict__ Wt3) {
    int i = blockIdx.x * blockDim.x + threadIdx.x;
    if (i < 32768) {                       // W1: [128][256]
        int k = i >> 8, m = i & 255;
        Wt1[m * 128 + k] = f2bf(W1[i]);
    } else if (i < 65536) {                // W2: [256][128]
        int j = i - 32768;
        int k = j >> 7, m = j & 127;
        Wt2[m * 256 + k] = f2bf(W2[j]);
    } else if (i < 73728) {                // W3: [128][64]
        int j = i - 65536;
        int k = j >> 6, m = j & 63;
        Wt3[m * 128 + k] = f2bf(W3[j]);
    }
}

// ---------------- CSR gather aggregation (bf16 in, bf16/f32 out) ----------------
// one 64-lane wave per dst node; cnt = rowp[n+1]-rowp[n]; 8 gathers in flight
template<int C, bool BIAS, bool RELU, bool LOGSM, bool OUTF32>
__global__ void agg_csr_kernel(const unsigned short* __restrict__ h,
                               const float* __restrict__ dinv,
                               const int* __restrict__ rowptr,
                               const int2* __restrict__ sedge,
                               const float* __restrict__ bias, void* __restrict__ outv) {
    constexpr int V = C / 64;  // 2 for C=128, 1 for C=64
    int gw = (int)((blockIdx.x * (long)blockDim.x + threadIdx.x) >> 6);
    int lane = threadIdx.x & 63;
    if (gw >= N_NODES) return;

    float di = dinv[gw];
    int st = rowptr[gw];
    int cnt = rowptr[gw + 1] - st;
    float a0, a1 = 0.0f;
    if constexpr (V == 2) {
        unsigned int u = ((const unsigned int*)(h + (long)gw * C))[lane];
        a0 = di * bflo2f(u); a1 = di * bfhi2f(u);
    } else {
        a0 = di * bflo2f(h[(long)gw * C + lane]);
    }

    int k = 0;
    for (; k + 8 <= cnt; k += 8) {
        int2 r[8];
#pragma unroll
        for (int j = 0; j < 8; ++j) r[j] = sedge[st + k + j];
        if constexpr (V == 2) {
            unsigned int u[8];
#pragma unroll
            for (int j = 0; j < 8; ++j)
                u[j] = ((const unsigned int*)(h + (long)r[j].x * C))[lane];
#pragma unroll
            for (int j = 0; j < 8; ++j) {
                float w = __int_as_float(r[j].y);
                a0 += w * bflo2f(u[j]); a1 += w * bfhi2f(u[j]);
            }
        } else {
            unsigned short u[8];
#pragma unroll
            for (int j = 0; j < 8; ++j)
                u[j] = h[(long)r[j].x * C + lane];
#pragma unroll
            for (int j = 0; j < 8; ++j)
                a0 += __int_as_float(r[j].y) * bflo2f(u[j]);
        }
    }
    for (; k + 4 <= cnt; k += 4) {
        int2 r[4];
#pragma unroll
        for (int j = 0; j < 4; ++j) r[j] = sedge[st + k + j];
        if constexpr (V == 2) {
            unsigned int u[4];
#pragma unroll
            for (int j = 0; j < 4; ++j)
                u[j] = ((const unsigned int*)(h + (long)r[j].x * C))[lane];
#pragma unroll
            for (int j = 0; j < 4; ++j) {
                float w = __int_as_float(r[j].y);
                a0 += w * bflo2f(u[j]); a1 += w * bfhi2f(u[j]);
            }
        } else {
            unsigned short u[4];
#pragma unroll
            for (int j = 0; j < 4; ++j)
                u[j] = h[(long)r[j].x * C + lane];
#pragma unroll
            for (int j = 0; j < 4; ++j)
                a0 += __int_as_float(r[j].y) * bflo2f(u[j]);
        }
    }
    for (; k < cnt; ++k) {
        int2 r = sedge[st + k];
        float w = __int_as_float(r.y);
        if constexpr (V == 2) {
            unsigned int u = ((const unsigned int*)(h + (long)r.x * C))[lane];
            a0 += w * bflo2f(u); a1 += w * bfhi2f(u);
        } else {
            a0 += w * bflo2f(h[(long)r.x * C + lane]);
        }
    }

    a0 *= di; a1 *= di;
    if constexpr (BIAS) {
        if constexpr (V == 2) { a0 += bias[lane * 2]; a1 += bias[lane * 2 + 1]; }
        else a0 += bias[lane];
    }
    if constexpr (RELU) { a0 = fmaxf(a0, 0.0f); a1 = fmaxf(a1, 0.0f); }
    if constexpr (LOGSM) {  // V==1 only
        float m = a0;
#pragma unroll
        for (int o = 32; o > 0; o >>= 1) m = fmaxf(m, __shfl_xor(m, o));
        float e = expf(a0 - m), s = e;
#pragma unroll
        for (int o = 32; o > 0; o >>= 1) s += __shfl_xor(s, o);
        a0 = a0 - m - logf(s);
    }
    if constexpr (OUTF32) {
        float* out = (float*)outv;
        if constexpr (V == 2) {
            float2 r; r.x = a0; r.y = a1;
            *(float2*)(out + (long)gw * C + lane * 2) = r;
        } else {
            out[(long)gw * C + lane] = a0;
        }
    } else {
        unsigned short* out = (unsigned short*)outv;
        if constexpr (V == 2) {
            unsigned int up = (unsigned int)f2bf(a0) | ((unsigned int)f2bf(a1) << 16);
            ((unsigned int*)(out + (long)gw * C))[lane] = up;
        } else {
            out[(long)gw * C + lane] = f2bf(a0);
        }
    }
}

// ---------------- bf16 MFMA GEMM, 64 x full-M tile ----------------
// A panel (64 x K) staged once in LDS (swizzled); B fragments read directly from
// global Wt[M][K] (tiny, L2-broadcast). 4 waves; wave wv owns cols [wv*M/4, ...).
template<int K, int M, bool BIAS, bool RELU>
__global__ __launch_bounds__(256) void gemm_mfma_kernel(
        const unsigned short* __restrict__ A,   // [NPAD][K]
        const unsigned short* __restrict__ Bt,  // [M][K]
        const float* __restrict__ bias,         // [M]
        unsigned short* __restrict__ Cb,        // [NPAD][M]
        int N) {
    constexpr int KC = K / 8;                    // 16B chunks per row
    constexpr int NT = M / 64;                   // col subtiles per wave (M/4/16)
    __shared__ unsigned short As[64 * K];

    int tid = threadIdx.x;
    int row0 = blockIdx.x * 64;
    const unsigned short* Ap = A + (long)row0 * K;

    // stage A panel; LDS byte = (c*16) ^ ((row&7)<<4)
    for (int c = tid; c < 64 * KC; c += 256) {
        int r = c / KC;
        unsigned int swz = ((unsigned int)c * 16u) ^ ((unsigned int)(r & 7) << 4);
        *(bf16x8*)((char*)As + swz) = *(const bf16x8*)(Ap + c * 8);
    }
    __syncthreads();

    int lane = tid & 63;
    int wv = tid >> 6;
    int lr = lane & 15;
    int kg = lane >> 4;                 // k-group: k = kg*8 + j
    int colbase = wv * (M / 4);

    // per-subtile B row pointers (global; same layout the LDS read had)
    const unsigned short* bp[NT];
#pragma unroll
    for (int ni = 0; ni < NT; ++ni)
        bp[ni] = Bt + (size_t)(colbase + ni * 16 + lr) * K + kg * 8;

    f32x4 acc[4][NT] = {};

    for (int k0 = 0; k0 < K; k0 += 32) {
        bf16x8 a[4], b[NT];
#pragma unroll
        for (int mi = 0; mi < 4; ++mi) {
            int r = mi * 16 + lr;
            unsigned int byteo = (unsigned int)((r * K + k0 + kg * 8) * 2);
            byteo ^= (unsigned int)((r & 7) << 4);
            a[mi] = *(const bf16x8*)((const char*)As + byteo);
        }
#pragma unroll
        for (int ni = 0; ni < NT; ++ni)
            b[ni] = *(const bf16x8*)(bp[ni] + k0);
#pragma unroll
        for (int mi = 0; mi < 4; ++mi)
#pragma unroll
            for (int ni = 0; ni < NT; ++ni)
                acc[mi][ni] = __builtin_amdgcn_mfma_f32_16x16x32_bf16(
                    a[mi], b[ni], acc[mi][ni], 0, 0, 0);
    }

    // epilogue: C/D layout col=lane&15, row=(lane>>4)*4+i
#pragma unroll
    for (int mi = 0; mi < 4; ++mi) {
#pragma unroll
        for (int ni = 0; ni < NT; ++ni) {
            int col = colbase + ni * 16 + lr;
            float bv = BIAS ? bias[col] : 0.0f;
#pragma unroll
            for (int i = 0; i < 4; ++i) {
                int row = row0 + mi * 16 + kg * 4 + i;
                if (row < N) {
                    float v = acc[mi][ni][i] + bv;
                    if (RELU) v = fmaxf(v, 0.0f);
                    Cb[(long)row * M + col] = f2bf(v);
                }
            }
        }
    }
}

// ---------------- launch ----------------

extern "C" void kernel_launch(void* const* d_in, const int* in_sizes, int n_in,
                              void* d_out, int out_size, void* d_ws, size_t ws_size,
                              hipStream_t stream) {
    const float* x  = (const float*)d_in[0];
    const int* edge = (const int*)d_in[1];
    const float* W1 = (const float*)d_in[2];
    const float* b1 = (const float*)d_in[3];
    const float* W2 = (const float*)d_in[4];
    const float* b2 = (const float*)d_in[5];
    const float* W3 = (const float*)d_in[6];
    const float* b3 = (const float*)d_in[7];
    float* out = (float*)d_out;

    const int* src = edge;
    const int* dst = edge + N_EDGES;

    // workspace layout (float-element offsets)
    float* ws    = (float*)d_ws;
    float* dinv  = ws;                                   // N
    int*   rowp  = (int*)(ws + 100000);                  // N+1 (alloc 100352)
    int*   btot  = (int*)(ws + 200352);                  // 391 (alloc 512)
    int*   bbase = (int*)(ws + 200864);                  // 391 (alloc 512)
    int*   bcnt  = (int*)(ws + 201376);                  // 391*391=152881 (alloc 153600)
    int2*  sedge = (int2*)(ws + 354976);                 // E*2 ints (8B aligned)
    unsigned short* P1  = (unsigned short*)(ws + 3554976);   // [NPAD][128]
    unsigned short* P2  = P1 + (size_t)NPAD * 128;           // [NPAD][128]
    unsigned short* P3  = P2 + (size_t)NPAD * 128;           // [NPAD][256]
    unsigned short* Wt1 = P3 + (size_t)NPAD * 256;           // [256][128]
    unsigned short* Wt2 = Wt1 + 128 * 256;                   // [128][256]
    unsigned short* Wt3 = Wt2 + 256 * 128;                   // [64][128]
    int*   part  = (int*)P3;   // scratch reuse: consumed before gemm1 writes P3

    const int BT = 256;
    int gAgg = (int)(((long)N_NODES * 64 + BT - 1) / BT);
    int gRows = (N_NODES + 63) / 64;   // 1563

    // --- bucket counts (reads dst once; LDS-only atomics) ---
    edge_count_kernel<<<NBLK_P, 1024, 0, stream>>>(dst, bcnt);

    // --- bucket scans + partition (packed 32-bit records) ---
    bucket_scan_kernel<<<NBUCK, 64, 0, stream>>>(bcnt, btot);
    bbase_scan_kernel<<<1, 512, 0, stream>>>(btot, bbase);
    part_scatter_kernel<<<NBLK_P, 1024, 0, stream>>>(src, dst, bcnt, bbase, part);

    // --- per-bucket degrees -> rowp + dinv; then coalesced CSR scatter ---
    bucket_deg_kernel<<<NBUCK, 512, 0, stream>>>(part, bbase, btot, rowp, dinv);
    final_scatter_lds_kernel<<<NBUCK, 512, 0, stream>>>(part, dinv, rowp, bbase, btot, sedge);

    // --- conversions ---
    cvt_x_kernel<<<(int)(((long)N_NODES * 128 / 4 + BT - 1) / BT), BT, 0, stream>>>(x, P1);
    cvt_w_all_kernel<<<(73728 + BT - 1) / BT, BT, 0, stream>>>(W1, W2, W3, Wt1, Wt2, Wt3);

    // --- layer 1: agg(x) [P1->P2], gemm 128->256 +b1 +relu [P2->P3] ---
    agg_csr_kernel<128, false, false, false, false><<<gAgg, BT, 0, stream>>>(
        P1, dinv, rowp, sedge, nullptr, P2);
    gemm_mfma_kernel<128, 256, true, true><<<gRows, BT, 0, stream>>>(P2, Wt1, b1, P3, N_NODES);

    // --- layer 2: gemm 256->128 [P3->P1], agg +b2 +relu [P1->P2] ---
    gemm_mfma_kernel<256, 128, false, false><<<gRows, BT, 0, stream>>>(P3, Wt2, nullptr, P1, N_NODES);
    agg_csr_kernel<128, true, true, false, false><<<gAgg, BT, 0, stream>>>(
        P1, dinv, rowp, sedge, b2, P2);

    // --- layer 3: gemm 128->64 [P2->P1], agg +b3 +relu +logsm [P1->out] ---
    gemm_mfma_kernel<128, 64, false, false><<<gRows, BT, 0, stream>>>(P2, Wt3, nullptr, P1, N_NODES);
    agg_csr_kernel<64, true, true, true, true><<<gAgg, BT, 0, stream>>>(
        P1, dinv, rowp, sedge, b3, out);

    (void)in_sizes; (void)n_in; (void)out_size; (void)ws_size;
}

// Round 12
// 308.950 us; speedup vs baseline: 3.3499x; 1.0763x over previous
//
#include <hip/hip_runtime.h>
#include <math.h>

#define N_NODES 100000
#define N_EDGES 1600000
#define CHUNK 4096
#define NBLK_P ((N_EDGES + CHUNK - 1) / CHUNK)  // 391
#define NPAD 100064                          // 64-row padded for GEMM staging
#define BSHIFT 8                             // 256 nodes per bucket
#define NBUCK ((N_NODES + 255) / 256)        // 391 buckets
#define BCAP 6144                            // LDS record capacity per bucket

typedef __attribute__((ext_vector_type(8))) short bf16x8;
typedef __attribute__((ext_vector_type(4))) float f32x4;

__device__ __forceinline__ unsigned short f2bf(float f) {
    unsigned int u = __builtin_bit_cast(unsigned int, f);
    u += 0x7fffu + ((u >> 16) & 1u);          // RNE
    return (unsigned short)(u >> 16);
}
__device__ __forceinline__ float bflo2f(unsigned int u) {   // low 16 bits = bf16
    return __builtin_bit_cast(float, u << 16);
}
__device__ __forceinline__ float bfhi2f(unsigned int u) {   // high 16 bits = bf16
    return __builtin_bit_cast(float, u & 0xffff0000u);
}

// ---------------- bucket count only (LDS atomics) ----------------

__global__ __launch_bounds__(1024) void edge_count_kernel(const int* __restrict__ dst,
                                                          int* __restrict__ bcnt) {
    __shared__ int lh[NBUCK];
    int tid = threadIdx.x;
    if (tid < NBUCK) lh[tid] = 0;
    __syncthreads();
    long base = (long)blockIdx.x * CHUNK;
#pragma unroll
    for (int p = 0; p < CHUNK; p += 1024) {
        long e = base + p + tid;
        if (e < N_EDGES) atomicAdd(&lh[dst[e] >> BSHIFT], 1);
    }
    __syncthreads();
    if (tid < NBUCK) bcnt[tid * NBLK_P + blockIdx.x] = lh[tid];
}

// ---------------- bucket scan over blocks (one wave per bucket) ----------------

__global__ void bucket_scan_kernel(int* __restrict__ bcnt, int* __restrict__ btot) {
    int bu = blockIdx.x, lane = threadIdx.x;   // 64 threads
    int base = 0;
    for (int i0 = 0; i0 < NBLK_P; i0 += 64) {
        int i = i0 + lane;
        int v = (i < NBLK_P) ? bcnt[bu * NBLK_P + i] : 0;
        int orig = v;
#pragma unroll
        for (int off = 1; off < 64; off <<= 1) {
            int t = __shfl_up(v, off);
            if (lane >= off) v += t;
        }
        if (i < NBLK_P) bcnt[bu * NBLK_P + i] = base + v - orig;
        base += __shfl(v, 63);
    }
    if (lane == 0) btot[bu] = base;
}

// parallel exclusive scan over NBUCK totals (single 512-thread block)
__global__ void bbase_scan_kernel(const int* __restrict__ btot, int* __restrict__ bbase) {
    __shared__ int tmp[512];
    int i = threadIdx.x;
    int v = (i < NBUCK) ? btot[i] : 0;
    tmp[i] = v;
    __syncthreads();
    for (int off = 1; off < 512; off <<= 1) {
        int t = (i >= off) ? tmp[i - off] : 0;
        __syncthreads();
        tmp[i] += t;
        __syncthreads();
    }
    if (i < NBUCK) bbase[i] = tmp[i] - v;
}

// ---------------- partition edges; record packed: src | (d&255)<<17 ----------------

__global__ __launch_bounds__(1024) void part_scatter_kernel(
        const int* __restrict__ src, const int* __restrict__ dst,
        const int* __restrict__ bcnt, const int* __restrict__ bbase,
        int* __restrict__ part) {
    __shared__ int lh[NBUCK];
    int tid = threadIdx.x;
    if (tid < NBUCK) lh[tid] = 0;
    __syncthreads();
    long base = (long)blockIdx.x * CHUNK;
#pragma unroll
    for (int p = 0; p < CHUNK; p += 1024) {
        long e = base + p + tid;
        if (e < N_EDGES) {
            int s = src[e], d = dst[e];
            int bu = d >> BSHIFT;
            int lr = atomicAdd(&lh[bu], 1);
            int pos = bbase[bu] + bcnt[bu * NBLK_P + blockIdx.x] + lr;
            part[pos] = s | ((d & 255) << 17);
        }
    }
}

// ---------------- per-bucket degrees -> rowp + dinv (LDS count + local scan) ----------------

__global__ __launch_bounds__(512) void bucket_deg_kernel(
        const int* __restrict__ part, const int* __restrict__ bbase,
        const int* __restrict__ btot, int* __restrict__ rowp,
        float* __restrict__ dinv) {
    __shared__ int lcnt[256];
    __shared__ int lscan[256];
    int b = blockIdx.x;
    int node0 = b << BSHIFT;
    int start = bbase[b];
    int cnt = btot[b];
    int tid = threadIdx.x;
    if (tid < 256) lcnt[tid] = 0;
    __syncthreads();
    for (int e = tid; e < cnt; e += 512)
        atomicAdd(&lcnt[part[start + e] >> 17], 1);
    __syncthreads();
    int v = 0;
    if (tid < 256) { v = lcnt[tid]; lscan[tid] = v; }
    __syncthreads();
    for (int off = 1; off < 256; off <<= 1) {
        int t = (tid < 256 && tid >= off) ? lscan[tid - off] : 0;
        __syncthreads();
        if (tid < 256) lscan[tid] += t;
        __syncthreads();
    }
    if (tid < 256) {
        int n = node0 + tid;
        if (n < N_NODES) {
            rowp[n] = start + lscan[tid] - v;      // exclusive prefix
            dinv[n] = rsqrtf(1.0f + (float)v);     // +1 self-loop
        }
    }
    if (b == NBUCK - 1 && tid == 0) rowp[N_NODES] = N_EDGES;
}

// ---------------- final scatter, LDS-staged per bucket: coalesced sedge writes ----------------

__global__ __launch_bounds__(512) void final_scatter_lds_kernel(
        const int* __restrict__ part, const float* __restrict__ dinv,
        const int* __restrict__ rowp, const int* __restrict__ bbase,
        const int* __restrict__ btot, int2* __restrict__ sedge) {
    __shared__ int lcurs[256];
    __shared__ int2 buf[BCAP];
    int b = blockIdx.x;
    int node0 = b << BSHIFT;
    int start = bbase[b];
    int cnt = btot[b];
    int tid = threadIdx.x;
    if (tid < 256) {
        int n = node0 + tid;
        lcurs[tid] = (n < N_NODES) ? (rowp[n] - start) : cnt;
    }
    __syncthreads();
    for (int e = tid; e < cnt; e += 512) {
        int r = part[start + e];
        int s = r & 0x1FFFF;
        int lpos = atomicAdd(&lcurs[r >> 17], 1);
        int2 rec; rec.x = s; rec.y = __float_as_int(dinv[s]);
        if (lpos < BCAP) buf[lpos] = rec;
        else sedge[start + lpos] = rec;   // statistical-impossibility fallback
    }
    __syncthreads();
    int lim = min(cnt, BCAP);
    for (int e = tid; e < lim; e += 512)
        sedge[start + e] = buf[e];
}

// ---------------- conversions ----------------

__global__ void cvt_x_kernel(const float* __restrict__ x, unsigned short* __restrict__ xb) {
    long i = (long)blockIdx.x * blockDim.x + threadIdx.x;   // over n/4
    if (i >= (long)N_NODES * 128 / 4) return;
    float4 v = ((const float4*)x)[i];
    ushort4 o;
    o.x = f2bf(v.x); o.y = f2bf(v.y); o.z = f2bf(v.z); o.w = f2bf(v.w);
    ((ushort4*)xb)[i] = o;
}

// all three weights, transposed+converted: Wt[m][k] = bf16(W[k][m])
__global__ void cvt_w_all_kernel(const float* __restrict__ W1, const float* __restrict__ W2,
                                 const float* __restrict__ W3,
                                 unsigned short* __restrict__ Wt1,
                                 unsigned short* __restrict__ Wt2,
                                 unsigned short* __restrict__ Wt3) {
    int i = blockIdx.x * blockDim.x + threadIdx.x;
    if (i < 32768) {                       // W1: [128][256]
        int k = i >> 8, m = i & 255;
        Wt1[m * 128 + k] = f2bf(W1[i]);
    } else if (i < 65536) {                // W2: [256][128]
        int j = i - 32768;
        int k = j >> 7, m = j & 127;
        Wt2[m * 256 + k] = f2bf(W2[j]);
    } else if (i < 73728) {                // W3: [128][64]
        int j = i - 65536;
        int k = j >> 6, m = j & 63;
        Wt3[m * 128 + k] = f2bf(W3[j]);
    }
}

// ---------------- CSR gather aggregation (bf16 in, bf16/f32 out) ----------------
// ONE WAVE PER BLOCK per dst node; 16 gathers in flight (latency-bound fix)
template<int C, bool BIAS, bool RELU, bool LOGSM, bool OUTF32>
__global__ __launch_bounds__(64) void agg_csr_kernel(
                               const unsigned short* __restrict__ h,
                               const float* __restrict__ dinv,
                               const int* __restrict__ rowptr,
                               const int2* __restrict__ sedge,
                               const float* __restrict__ bias, void* __restrict__ outv) {
    constexpr int V = C / 64;  // 2 for C=128, 1 for C=64
    int gw = blockIdx.x;
    int lane = threadIdx.x;
    if (gw >= N_NODES) return;

    float di = dinv[gw];
    int st = rowptr[gw];
    int cnt = rowptr[gw + 1] - st;
    float a0, a1 = 0.0f;
    if constexpr (V == 2) {
        unsigned int u = ((const unsigned int*)(h + (long)gw * C))[lane];
        a0 = di * bflo2f(u); a1 = di * bfhi2f(u);
    } else {
        a0 = di * bflo2f(h[(long)gw * C + lane]);
    }

    int k = 0;
    // 16-deep gather block
    for (; k + 16 <= cnt; k += 16) {
        int2 r[16];
#pragma unroll
        for (int j = 0; j < 16; ++j) r[j] = sedge[st + k + j];
        if constexpr (V == 2) {
            unsigned int u[16];
#pragma unroll
            for (int j = 0; j < 16; ++j)
                u[j] = ((const unsigned int*)(h + (long)r[j].x * C))[lane];
#pragma unroll
            for (int j = 0; j < 16; ++j) {
                float w = __int_as_float(r[j].y);
                a0 += w * bflo2f(u[j]); a1 += w * bfhi2f(u[j]);
            }
        } else {
            unsigned short u[16];
#pragma unroll
            for (int j = 0; j < 16; ++j)
                u[j] = h[(long)r[j].x * C + lane];
#pragma unroll
            for (int j = 0; j < 16; ++j)
                a0 += __int_as_float(r[j].y) * bflo2f(u[j]);
        }
    }
    // 8-deep
    for (; k + 8 <= cnt; k += 8) {
        int2 r[8];
#pragma unroll
        for (int j = 0; j < 8; ++j) r[j] = sedge[st + k + j];
        if constexpr (V == 2) {
            unsigned int u[8];
#pragma unroll
            for (int j = 0; j < 8; ++j)
                u[j] = ((const unsigned int*)(h + (long)r[j].x * C))[lane];
#pragma unroll
            for (int j = 0; j < 8; ++j) {
                float w = __int_as_float(r[j].y);
                a0 += w * bflo2f(u[j]); a1 += w * bfhi2f(u[j]);
            }
        } else {
            unsigned short u[8];
#pragma unroll
            for (int j = 0; j < 8; ++j)
                u[j] = h[(long)r[j].x * C + lane];
#pragma unroll
            for (int j = 0; j < 8; ++j)
                a0 += __int_as_float(r[j].y) * bflo2f(u[j]);
        }
    }
    // 4-deep
    for (; k + 4 <= cnt; k += 4) {
        int2 r[4];
#pragma unroll
        for (int j = 0; j < 4; ++j) r[j] = sedge[st + k + j];
        if constexpr (V == 2) {
            unsigned int u[4];
#pragma unroll
            for (int j = 0; j < 4; ++j)
                u[j] = ((const unsigned int*)(h + (long)r[j].x * C))[lane];
#pragma unroll
            for (int j = 0; j < 4; ++j) {
                float w = __int_as_float(r[j].y);
                a0 += w * bflo2f(u[j]); a1 += w * bfhi2f(u[j]);
            }
        } else {
            unsigned short u[4];
#pragma unroll
            for (int j = 0; j < 4; ++j)
                u[j] = h[(long)r[j].x * C + lane];
#pragma unroll
            for (int j = 0; j < 4; ++j)
                a0 += __int_as_float(r[j].y) * bflo2f(u[j]);
        }
    }
    // tail
    for (; k < cnt; ++k) {
        int2 r = sedge[st + k];
        float w = __int_as_float(r.y);
        if constexpr (V == 2) {
            unsigned int u = ((const unsigned int*)(h + (long)r.x * C))[lane];
            a0 += w * bflo2f(u); a1 += w * bfhi2f(u);
        } else {
            a0 += w * bflo2f(h[(long)r.x * C + lane]);
        }
    }

    a0 *= di; a1 *= di;
    if constexpr (BIAS) {
        if constexpr (V == 2) { a0 += bias[lane * 2]; a1 += bias[lane * 2 + 1]; }
        else a0 += bias[lane];
    }
    if constexpr (RELU) { a0 = fmaxf(a0, 0.0f); a1 = fmaxf(a1, 0.0f); }
    if constexpr (LOGSM) {  // V==1 only
        float m = a0;
#pragma unroll
        for (int o = 32; o > 0; o >>= 1) m = fmaxf(m, __shfl_xor(m, o));
        float e = expf(a0 - m), s = e;
#pragma unroll
        for (int o = 32; o > 0; o >>= 1) s += __shfl_xor(s, o);
        a0 = a0 - m - logf(s);
    }
    if constexpr (OUTF32) {
        float* out = (float*)outv;
        if constexpr (V == 2) {
            float2 r; r.x = a0; r.y = a1;
            *(float2*)(out + (long)gw * C + lane * 2) = r;
        } else {
            out[(long)gw * C + lane] = a0;
        }
    } else {
        unsigned short* out = (unsigned short*)outv;
        if constexpr (V == 2) {
            unsigned int up = (unsigned int)f2bf(a0) | ((unsigned int)f2bf(a1) << 16);
            ((unsigned int*)(out + (long)gw * C))[lane] = up;
        } else {
            out[(long)gw * C + lane] = f2bf(a0);
        }
    }
}

// ---------------- bf16 MFMA GEMM, 64 x full-M tile ----------------
template<int K, int M, bool BIAS, bool RELU>
__global__ __launch_bounds__(256) void gemm_mfma_kernel(
        const unsigned short* __restrict__ A,   // [NPAD][K]
        const unsigned short* __restrict__ Bt,  // [M][K]
        const float* __restrict__ bias,         // [M]
        unsigned short* __restrict__ Cb,        // [NPAD][M]
        int N) {
    constexpr int KC = K / 8;                    // 16B chunks per row
    constexpr int NT = M / 64;                   // col subtiles per wave (M/4/16)
    __shared__ unsigned short As[64 * K];

    int tid = threadIdx.x;
    int row0 = blockIdx.x * 64;
    const unsigned short* Ap = A + (long)row0 * K;

    // stage A panel; LDS byte = (c*16) ^ ((row&7)<<4)
    for (int c = tid; c < 64 * KC; c += 256) {
        int r = c / KC;
        unsigned int swz = ((unsigned int)c * 16u) ^ ((unsigned int)(r & 7) << 4);
        *(bf16x8*)((char*)As + swz) = *(const bf16x8*)(Ap + c * 8);
    }
    __syncthreads();

    int lane = tid & 63;
    int wv = tid >> 6;
    int lr = lane & 15;
    int kg = lane >> 4;                 // k-group: k = kg*8 + j
    int colbase = wv * (M / 4);

    const unsigned short* bp[NT];
#pragma unroll
    for (int ni = 0; ni < NT; ++ni)
        bp[ni] = Bt + (size_t)(colbase + ni * 16 + lr) * K + kg * 8;

    f32x4 acc[4][NT] = {};

    for (int k0 = 0; k0 < K; k0 += 32) {
        bf16x8 a[4], b[NT];
#pragma unroll
        for (int mi = 0; mi < 4; ++mi) {
            int r = mi * 16 + lr;
            unsigned int byteo = (unsigned int)((r * K + k0 + kg * 8) * 2);
            byteo ^= (unsigned int)((r & 7) << 4);
            a[mi] = *(const bf16x8*)((const char*)As + byteo);
        }
#pragma unroll
        for (int ni = 0; ni < NT; ++ni)
            b[ni] = *(const bf16x8*)(bp[ni] + k0);
#pragma unroll
        for (int mi = 0; mi < 4; ++mi)
#pragma unroll
            for (int ni = 0; ni < NT; ++ni)
                acc[mi][ni] = __builtin_amdgcn_mfma_f32_16x16x32_bf16(
                    a[mi], b[ni], acc[mi][ni], 0, 0, 0);
    }

    // epilogue: C/D layout col=lane&15, row=(lane>>4)*4+i
#pragma unroll
    for (int mi = 0; mi < 4; ++mi) {
#pragma unroll
        for (int ni = 0; ni < NT; ++ni) {
            int col = colbase + ni * 16 + lr;
            float bv = BIAS ? bias[col] : 0.0f;
#pragma unroll
            for (int i = 0; i < 4; ++i) {
                int row = row0 + mi * 16 + kg * 4 + i;
                if (row < N) {
                    float v = acc[mi][ni][i] + bv;
                    if (RELU) v = fmaxf(v, 0.0f);
                    Cb[(long)row * M + col] = f2bf(v);
                }
            }
        }
    }
}

// ---------------- launch ----------------

extern "C" void kernel_launch(void* const* d_in, const int* in_sizes, int n_in,
                              void* d_out, int out_size, void* d_ws, size_t ws_size,
                              hipStream_t stream) {
    const float* x  = (const float*)d_in[0];
    const int* edge = (const int*)d_in[1];
    const float* W1 = (const float*)d_in[2];
    const float* b1 = (const float*)d_in[3];
    const float* W2 = (const float*)d_in[4];
    const float* b2 = (const float*)d_in[5];
    const float* W3 = (const float*)d_in[6];
    const float* b3 = (const float*)d_in[7];
    float* out = (float*)d_out;

    const int* src = edge;
    const int* dst = edge + N_EDGES;

    // workspace layout (float-element offsets)
    float* ws    = (float*)d_ws;
    float* dinv  = ws;                                   // N
    int*   rowp  = (int*)(ws + 100000);                  // N+1 (alloc 100352)
    int*   btot  = (int*)(ws + 200352);                  // 391 (alloc 512)
    int*   bbase = (int*)(ws + 200864);                  // 391 (alloc 512)
    int*   bcnt  = (int*)(ws + 201376);                  // 391*391=152881 (alloc 153600)
    int2*  sedge = (int2*)(ws + 354976);                 // E*2 ints (8B aligned)
    unsigned short* P1  = (unsigned short*)(ws + 3554976);   // [NPAD][128]
    unsigned short* P2  = P1 + (size_t)NPAD * 128;           // [NPAD][128]
    unsigned short* P3  = P2 + (size_t)NPAD * 128;           // [NPAD][256]
    unsigned short* Wt1 = P3 + (size_t)NPAD * 256;           // [256][128]
    unsigned short* Wt2 = Wt1 + 128 * 256;                   // [128][256]
    unsigned short* Wt3 = Wt2 + 256 * 128;                   // [64][128]
    int*   part  = (int*)P3;   // scratch reuse: consumed before gemm1 writes P3

    const int BT = 256;
    int gRows = (N_NODES + 63) / 64;   // 1563

    // --- bucket counts (reads dst once; LDS-only atomics) ---
    edge_count_kernel<<<NBLK_P, 1024, 0, stream>>>(dst, bcnt);

    // --- bucket scans + partition (packed 32-bit records) ---
    bucket_scan_kernel<<<NBUCK, 64, 0, stream>>>(bcnt, btot);
    bbase_scan_kernel<<<1, 512, 0, stream>>>(btot, bbase);
    part_scatter_kernel<<<NBLK_P, 1024, 0, stream>>>(src, dst, bcnt, bbase, part);

    // --- per-bucket degrees -> rowp + dinv; then coalesced CSR scatter ---
    bucket_deg_kernel<<<NBUCK, 512, 0, stream>>>(part, bbase, btot, rowp, dinv);
    final_scatter_lds_kernel<<<NBUCK, 512, 0, stream>>>(part, dinv, rowp, bbase, btot, sedge);

    // --- conversions ---
    cvt_x_kernel<<<(int)(((long)N_NODES * 128 / 4 + BT - 1) / BT), BT, 0, stream>>>(x, P1);
    cvt_w_all_kernel<<<(73728 + BT - 1) / BT, BT, 0, stream>>>(W1, W2, W3, Wt1, Wt2, Wt3);

    // --- layer 1: agg(x) [P1->P2], gemm 128->256 +b1 +relu [P2->P3] ---
    agg_csr_kernel<128, false, false, false, false><<<N_NODES, 64, 0, stream>>>(
        P1, dinv, rowp, sedge, nullptr, P2);
    gemm_mfma_kernel<128, 256, true, true><<<gRows, BT, 0, stream>>>(P2, Wt1, b1, P3, N_NODES);

    // --- layer 2: gemm 256->128 [P3->P1], agg +b2 +relu [P1->P2] ---
    gemm_mfma_kernel<256, 128, false, false><<<gRows, BT, 0, stream>>>(P3, Wt2, nullptr, P1, N_NODES);
    agg_csr_kernel<128, true, true, false, false><<<N_NODES, 64, 0, stream>>>(
        P1, dinv, rowp, sedge, b2, P2);

    // --- layer 3: gemm 128->64 [P2->P1], agg +b3 +relu +logsm [P1->out] ---
    gemm_mfma_kernel<128, 64, false, false><<<gRows, BT, 0, stream>>>(P2, Wt3, nullptr, P1, N_NODES);
    agg_csr_kernel<64, true, true, true, true><<<N_NODES, 64, 0, stream>>>(
        P1, dinv, rowp, sedge, b3, out);

    (void)in_sizes; (void)n_in; (void)out_size; (void)ws_size;
}